// Round 10
// baseline (273.544 us; speedup 1.0000x reference)
//
#include <hip/hip_runtime.h>
#include <hip/hip_bf16.h>
#include <math.h>

#define HN 8
#define DM 512
#define DHD 64
#define FFD 2048
#define BB 2
#define SS 4096
#define MT (BB*SS)   // 8192 token rows

typedef __bf16 bf16_t;
typedef __bf16 bf16x8 __attribute__((ext_vector_type(8)));
typedef __bf16 bf16x4 __attribute__((ext_vector_type(4)));
typedef float  floatx4 __attribute__((ext_vector_type(4)));

// Async global->LDS. NOTE (m104/m108): LDS dest is wave-uniform base + lane*16;
// all swizzling must be applied on the GLOBAL SOURCE side, LDS dest stays linear.
__device__ __forceinline__ void async_copy16(const bf16_t* g, bf16_t* l) {
  __builtin_amdgcn_global_load_lds((const __attribute__((address_space(1))) void*)g,
                                   (__attribute__((address_space(3))) void*)l,
                                   16, 0, 0);
}

#if __has_builtin(__builtin_amdgcn_exp2f)
__device__ __forceinline__ float fast_exp2(float x) { return __builtin_amdgcn_exp2f(x); }
#else
__device__ __forceinline__ float fast_exp2(float x) { return __expf(x * 0.69314718056f); }
#endif

// tanh-form GELU via exp2 (max |err| vs exact erf-GELU ~3e-3, ~10 VALU ops)
__device__ __forceinline__ float gelu_f(float x) {
  float y = 0.7978845608f * (x + 0.044715f * x * x * x);
  float e = fast_exp2(y * 2.885390082f);   // exp(2y)
  float th = 1.0f - 2.0f / (e + 1.0f);
  return 0.5f * x * (1.0f + th);
}

// ---- Merged LN1 + weight-prep: independent prologue work, one dispatch ----
// blocks 0..2047: LayerNorm rows (4/block); blocks 2048..5119: transposes.
__global__ __launch_bounds__(256)
void prep_ln(const float* __restrict__ x, const float* __restrict__ g,
             const float* __restrict__ be, bf16_t* __restrict__ out,
             const float* __restrict__ Wq, const float* __restrict__ Wk,
             const float* __restrict__ Wv, const float* __restrict__ Wo,
             const float* __restrict__ W1, const float* __restrict__ W2,
             bf16_t* __restrict__ WqkvT, bf16_t* __restrict__ WoT,
             bf16_t* __restrict__ W1T, bf16_t* __restrict__ W2T)
{
  __shared__ float tile[32][33];
  if (blockIdx.x < 2048) {
    const int wave = threadIdx.x >> 6, lane = threadIdx.x & 63;
    const int row = blockIdx.x * 4 + wave;
    const float* xr = x + (size_t)row * DM + lane * 8;
    float4 a = *(const float4*)xr;
    float4 c = *(const float4*)(xr + 4);
    float s  = (a.x + a.y) + (a.z + a.w) + (c.x + c.y) + (c.z + c.w);
    float s2 = (a.x*a.x + a.y*a.y) + (a.z*a.z + a.w*a.w)
             + (c.x*c.x + c.y*c.y) + (c.z*c.z + c.w*c.w);
#pragma unroll
    for (int o = 1; o < 64; o <<= 1) { s += __shfl_xor(s, o); s2 += __shfl_xor(s2, o); }
    const float mu = s * (1.0f / DM);
    const float rv = rsqrtf(s2 * (1.0f / DM) - mu * mu + 1e-5f);
    float4 g0 = *(const float4*)(g + lane * 8);
    float4 g1 = *(const float4*)(g + lane * 8 + 4);
    float4 b0 = *(const float4*)(be + lane * 8);
    float4 b1 = *(const float4*)(be + lane * 8 + 4);
    bf16x8 o8;
    o8[0] = (bf16_t)((a.x - mu) * rv * g0.x + b0.x);
    o8[1] = (bf16_t)((a.y - mu) * rv * g0.y + b0.y);
    o8[2] = (bf16_t)((a.z - mu) * rv * g0.z + b0.z);
    o8[3] = (bf16_t)((a.w - mu) * rv * g0.w + b0.w);
    o8[4] = (bf16_t)((c.x - mu) * rv * g1.x + b1.x);
    o8[5] = (bf16_t)((c.y - mu) * rv * g1.y + b1.y);
    o8[6] = (bf16_t)((c.z - mu) * rv * g1.z + b1.z);
    o8[7] = (bf16_t)((c.w - mu) * rv * g1.w + b1.w);
    *(bf16x8*)(out + (size_t)row * DM + lane * 8) = o8;
    return;
  }
  const int bid = blockIdx.x - 2048;
  const float* src; bf16_t* dst; int Kd, Nd, n0, k0;
  if (bid < 768) {
    int seg = bid >> 8, t = bid & 255;
    src = (seg == 0) ? Wq : (seg == 1) ? Wk : Wv;
    dst = WqkvT + (size_t)seg * 512 * 512;
    Kd = 512; Nd = 512; n0 = (t & 15) * 32; k0 = (t >> 4) * 32;
  } else if (bid < 1024) {
    int t = bid - 768; src = Wo; dst = WoT;
    Kd = 512; Nd = 512; n0 = (t & 15) * 32; k0 = (t >> 4) * 32;
  } else if (bid < 2048) {
    int t = bid - 1024; src = W1; dst = W1T;
    Kd = 512; Nd = 2048; n0 = (t & 63) * 32; k0 = (t >> 6) * 32;
  } else {
    int t = bid - 2048; src = W2; dst = W2T;
    Kd = 2048; Nd = 512; n0 = (t & 15) * 32; k0 = (t >> 4) * 32;
  }
  const int tx = threadIdx.x & 31, ty = threadIdx.x >> 5;
#pragma unroll
  for (int i = 0; i < 32; i += 8)
    tile[ty + i][tx] = src[(size_t)(k0 + ty + i) * Nd + n0 + tx];
  __syncthreads();
#pragma unroll
  for (int i = 0; i < 32; i += 8)
    dst[(size_t)(n0 + ty + i) * Kd + k0 + tx] = (bf16_t)tile[tx][ty + i];
}

// ------- LayerNorm: fp32 in -> bf16 out; 1 wave per row, 4 rows/block -------
__global__ __launch_bounds__(256)
void ln_kernel(const float* __restrict__ x, const float* __restrict__ g,
               const float* __restrict__ be, bf16_t* __restrict__ out)
{
  const int wave = threadIdx.x >> 6, lane = threadIdx.x & 63;
  const int row = blockIdx.x * 4 + wave;
  const float* xr = x + (size_t)row * DM + lane * 8;
  float4 a = *(const float4*)xr;
  float4 c = *(const float4*)(xr + 4);
  float s  = (a.x + a.y) + (a.z + a.w) + (c.x + c.y) + (c.z + c.w);
  float s2 = (a.x*a.x + a.y*a.y) + (a.z*a.z + a.w*a.w)
           + (c.x*c.x + c.y*c.y) + (c.z*c.z + c.w*c.w);
#pragma unroll
  for (int o = 1; o < 64; o <<= 1) { s += __shfl_xor(s, o); s2 += __shfl_xor(s2, o); }
  const float mu = s * (1.0f / DM);
  const float rv = rsqrtf(s2 * (1.0f / DM) - mu * mu + 1e-5f);
  float4 g0 = *(const float4*)(g + lane * 8);
  float4 g1 = *(const float4*)(g + lane * 8 + 4);
  float4 b0 = *(const float4*)(be + lane * 8);
  float4 b1 = *(const float4*)(be + lane * 8 + 4);
  bf16x8 o8;
  o8[0] = (bf16_t)((a.x - mu) * rv * g0.x + b0.x);
  o8[1] = (bf16_t)((a.y - mu) * rv * g0.y + b0.y);
  o8[2] = (bf16_t)((a.z - mu) * rv * g0.z + b0.z);
  o8[3] = (bf16_t)((a.w - mu) * rv * g0.w + b0.w);
  o8[4] = (bf16_t)((c.x - mu) * rv * g1.x + b1.x);
  o8[5] = (bf16_t)((c.y - mu) * rv * g1.y + b1.y);
  o8[6] = (bf16_t)((c.z - mu) * rv * g1.z + b1.z);
  o8[7] = (bf16_t)((c.w - mu) * rv * g1.w + b1.w);
  *(bf16x8*)(out + (size_t)row * DM + lane * 8) = o8;
}

// ---------------- GEMM: C[M,N] = A[M,K] * Bt[N,K]^T, bf16 MFMA --------------
// R1 structure (single-buffer, already one scheduling region -> pipelining
// variants were null R3/R6). BKT=128 ONLY where the grid limits occupancy to
// 2 blocks/CU AND LDS at BK=128 fits twice (<=80KB/block): FFN2 (K=2048,
// proven -7us R9) and Wo (K=512, (4,2)=48KB). QKV/FFN1 (4,4) would need
// 64KB -> m132 occupancy cliff -> stay BK=64.
// Staging map: flat chunk f covers row f/CH, chunk f%CH (CH=BKT/8); source
// col XOR'd by (row & (CH-1)); read chunk (c*4+quad)^(l16&(CH-1)) -> 2-way
// bank aliasing max (free, m136).
// EPI: 2 = f32 gelu(acc+bias)+res; 3 = bf16 gelu(acc+bias); 4 = f32 acc+bias+res
//      5 = fused-QKV epilogue (q scaled, k row-major, v transposed+sigma-permuted)
template <int MI, int NJ, int EPI, int BKT = 64>
__global__ __launch_bounds__(256)
void gemm_bt(const bf16_t* __restrict__ A, const bf16_t* __restrict__ Bt,
             const int M, const int N, const int K,
             const float* __restrict__ bias, const float* __restrict__ res,
             bf16_t* __restrict__ outb, float* __restrict__ outf,
             bf16_t* __restrict__ out2, bf16_t* __restrict__ out3, const int ldt)
{
  constexpr int MTILE = 32 * MI, NTILE = 32 * NJ;
  constexpr int CH = BKT / 8;                 // 16B chunks per row
  constexpr int ACOPY = MTILE * BKT / 2048;   // copy16 per thread per K-step
  constexpr int BCOPY = NTILE * BKT / 2048;
  __shared__ __align__(16) bf16_t lA[MTILE * BKT];
  __shared__ __align__(16) bf16_t lB[NTILE * BKT];
  const int tid = threadIdx.x;
  const int wave = tid >> 6, lane = tid & 63;
  const int wm = wave & 1, wn = wave >> 1;
  const int quad = lane >> 4, l16 = lane & 15;

  int srA[ACOPY > BCOPY ? ACOPY : BCOPY], scA[ACOPY > BCOPY ? ACOPY : BCOPY];
#pragma unroll
  for (int i = 0; i < (ACOPY > BCOPY ? ACOPY : BCOPY); ++i) {
    int flat = tid + 256 * i;
    int r = flat / CH, ch = flat % CH;
    srA[i] = r;
    scA[i] = (ch ^ (r & (CH - 1))) * 8;  // source-side swizzle, dest stays linear
  }
  const bf16_t* Ab = A + (size_t)(blockIdx.x * MTILE) * K;
  const bf16_t* Bb = Bt + (size_t)(blockIdx.y * NTILE) * K;

  const floatx4 vzero = {0.f, 0.f, 0.f, 0.f};
  floatx4 acc[MI][NJ];
#pragma unroll
  for (int i = 0; i < MI; ++i)
#pragma unroll
    for (int j = 0; j < NJ; ++j) acc[i][j] = vzero;

  for (int k0 = 0; k0 < K; k0 += BKT) {
    __syncthreads();
#pragma unroll
    for (int i = 0; i < ACOPY; ++i)
      async_copy16(Ab + (size_t)srA[i] * K + k0 + scA[i], lA + (tid + 256 * i) * 8);
#pragma unroll
    for (int i = 0; i < BCOPY; ++i)
      async_copy16(Bb + (size_t)srA[i] * K + k0 + scA[i], lB + (tid + 256 * i) * 8);
    __syncthreads();
#pragma unroll
    for (int c = 0; c < BKT / 32; ++c) {
      bf16x8 af[MI], bfv[NJ];
#pragma unroll
      for (int i = 0; i < MI; ++i)
        af[i] = *(const bf16x8*)(lA + (wm * 16 * MI + i * 16 + l16) * BKT
                                 + (((c * 4 + quad) ^ (l16 & (CH - 1))) * 8));
#pragma unroll
      for (int j = 0; j < NJ; ++j)
        bfv[j] = *(const bf16x8*)(lB + (wn * 16 * NJ + j * 16 + l16) * BKT
                                  + (((c * 4 + quad) ^ (l16 & (CH - 1))) * 8));
#pragma unroll
      for (int i = 0; i < MI; ++i)
#pragma unroll
        for (int j = 0; j < NJ; ++j)
          acc[i][j] = __builtin_amdgcn_mfma_f32_16x16x32_bf16(af[i], bfv[j], acc[i][j], 0, 0, 0);
    }
  }

  const int m00 = blockIdx.x * MTILE + wm * 16 * MI;
  const int n00 = blockIdx.y * NTILE + wn * 16 * NJ;
#pragma unroll
  for (int i = 0; i < MI; ++i) {
#pragma unroll
    for (int j = 0; j < NJ; ++j) {
      const int m0 = m00 + i * 16 + quad * 4;     // C/D: row=quad*4+reg, col=l16
      const int n  = n00 + j * 16 + l16;
      floatx4 v = acc[i][j];
      if (EPI == 2) {
        const float bb = bias[n];
#pragma unroll
        for (int r = 0; r < 4; ++r)
          outf[(size_t)(m0 + r) * N + n] = gelu_f(v[r] + bb) + res[(size_t)(m0 + r) * N + n];
      } else if (EPI == 3) {
        const float bb = bias[n];
#pragma unroll
        for (int r = 0; r < 4; ++r)
          outb[(size_t)(m0 + r) * N + n] = (bf16_t)gelu_f(v[r] + bb);
      } else if (EPI == 4) {
        const float bb = bias[n];
#pragma unroll
        for (int r = 0; r < 4; ++r)
          outf[(size_t)(m0 + r) * N + n] = v[r] + bb + res[(size_t)(m0 + r) * N + n];
      } else { // EPI 5: fused QKV
        const int seg = blockIdx.y >> 2;          // 0=Q 1=K 2=V (uniform per block)
        if (seg == 0) {
          // fold softmax scale (1/sqrt(64) * log2(e)) into Q, exact in fp32
#pragma unroll
          for (int r = 0; r < 4; ++r)
            outb[(size_t)(m0 + r) * 512 + n] = (bf16_t)(v[r] * 0.180336879f);
        } else if (seg == 1) {
#pragma unroll
          for (int r = 0; r < 4; ++r) out2[(size_t)(m0 + r) * 512 + (n - 512)] = (bf16_t)v[r];
        } else {
          // sigma-permute keys within 32-groups so attn PV A-frags are contiguous:
          // stored p = (o&3) + ((o>>2)&3)*8 + ((o>>4)&1)*4, o = m0&31 (mult of 4)
          const int o = m0 & 31;
          const int p0 = (m0 & ~31) + ((o >> 2) & 3) * 8 + ((o >> 4) << 2);
          bf16x4 pk = {(bf16_t)v[0], (bf16_t)v[1], (bf16_t)v[2], (bf16_t)v[3]};
          *(bf16x4*)(out3 + (size_t)(n - 1024) * ldt + p0) = pk;
        }
      }
    }
  }
}

// ---------------- Flash attention: Q-tile 128, 4 waves x 32 q-rows ----------
// Structure = R1 (32 q-rows/wave, 128-key dbuf, 2/CU) + R7 branch-free
// specialization + R10 one-chunk-ahead QK software pipeline:
// per chunk: issue ds_reads(c+1) -> exp(c) (covers ~120cy LDS latency) ->
// QK(c+1) MFMA (fills matrix pipe while pf packs) -> PV(c). sa/sb double-
// buffered (+16 VGPR). setprio pins REMOVED from the hot loop: s_setprio is
// side-effecting, so the scheduler couldn't migrate MFMAs across the old
// [QK][exp][PV] region boundaries (R7 theory, extended).
// Key-split variants DEAD (R5 spill / R8 1-wave-per-SIMD at >256 regs).
// S^T = mfma(K-frag, Q-frag): C-layout rows=keys (quad*4+r), cols=qrow (l16).
// kappa-permuted K=32 PV: B-operand = concat of two exp2'd S^T C-regs;
// sigma-permuted V^T makes each PV A-frag one contiguous b128 read.
// XCD swizzle: blocks sharing one (b,h)'s K/V cluster onto one XCD's L2.
__global__ __launch_bounds__(256, 2)
void attn_kernel(const bf16_t* __restrict__ qm, const bf16_t* __restrict__ km,
                 const bf16_t* __restrict__ vtm, const int* __restrict__ mask,
                 bf16_t* __restrict__ ctx)
{
  // dispatch d -> XCD d%8 (round-robin); give XCD j the contiguous range
  // [j*64, j*64+64) = 2 full (b,h) groups. Bijective (512%8==0).
  const int flat = blockIdx.x + 32 * (blockIdx.y + 8 * blockIdx.z);
  const int swz = (flat & 7) * 64 + (flat >> 3);
  const int b = swz >> 8, h = (swz >> 5) & 7;
  const int q0 = (swz & 31) * 128;
  const int tid = threadIdx.x;
  const int wave = tid >> 6, lane = tid & 63;
  const int quad = lane >> 4, l16 = lane & 15;

  __shared__ __align__(16) bf16_t lK[2][128 * DHD];   // [buf][key][dh]        2x16 KB
  __shared__ __align__(16) bf16_t lV[2][DHD * 128];   // [buf][dh][stored key] 2x16 KB
  __shared__ int sclean[4];

  const int* maskb = mask + b * SS;

  // ---- block-level mask pre-check: umin over all 4096 ints ----
  unsigned um = 0xFFFFFFFFu;
#pragma unroll
  for (int i = 0; i < 4; ++i) {
    int4 m = *(const int4*)(maskb + tid * 16 + i * 4);
    um = min(um, min(min((unsigned)m.x, (unsigned)m.y), min((unsigned)m.z, (unsigned)m.w)));
  }
#pragma unroll
  for (int o = 1; o < 64; o <<= 1) um = min(um, (unsigned)__shfl_xor((int)um, o));
  if (lane == 0) sclean[wave] = (int)um;
  __syncthreads();
  const bool clean = (min(min((unsigned)sclean[0], (unsigned)sclean[1]),
                          min((unsigned)sclean[2], (unsigned)sclean[3])) != 0u);

  const size_t qrow0 = (size_t)b * SS + q0;
  // Q as B-operand frags (n=qrow=l16, k=dh=quad*8+t), pre-scaled by softmax factor
  bf16x8 qa[2][2];
#pragma unroll
  for (int mb = 0; mb < 2; ++mb)
#pragma unroll
    for (int cc = 0; cc < 2; ++cc)
      qa[mb][cc] = *(const bf16x8*)(qm + (qrow0 + wave * 32 + mb * 16 + l16) * DM
                                    + h * DHD + cc * 32 + quad * 8);

  const floatx4 vzero = {0.f, 0.f, 0.f, 0.f};
  floatx4 cacc[2][4];
  float lsum[2] = {0.f, 0.f};
#pragma unroll
  for (int mb = 0; mb < 2; ++mb)
#pragma unroll
    for (int nb = 0; nb < 4; ++nb) cacc[mb][nb] = vzero;

  const bf16_t* Kb = km + (size_t)b * SS * DM + h * DHD;
  const bf16_t* Vb = vtm + (size_t)(h * DHD) * MT + (size_t)b * SS;

  // ---- precomputed per-thread staging pointers (source-side XOR swizzle) ----
  const bf16_t* pk[4]; const bf16_t* pv[4];
#pragma unroll
  for (int i = 0; i < 4; ++i) {
    int p = tid + 256 * i;
    int key = p >> 3, cs = (p & 7) ^ (key & 7);
    pk[i] = Kb + (size_t)key * DM + cs * 8;
    int dh = p >> 4, cs2 = (p & 15) ^ (dh & 7);
    pv[i] = Vb + (size_t)dh * MT + cs2 * 8;
  }

  auto stage = [&](int buf, int s0) {
#pragma unroll
    for (int i = 0; i < 4; ++i) {
      int p8 = (tid + 256 * i) * 8;
      async_copy16(pk[i] + (size_t)s0 * DM, lK[buf] + p8);
      async_copy16(pv[i] + s0, lV[buf] + p8);
    }
  };

  // shared exp2->pf->PV tail (masked fallback path only)
  auto exp_pv = [&](floatx4 sa[2], floatx4 sb[2], const bf16x8 av[4]) {
    bf16x8 pf[2];
#pragma unroll
    for (int mb = 0; mb < 2; ++mb) {
      float e0 = fast_exp2(sa[mb][0]), e1 = fast_exp2(sa[mb][1]);
      float e2 = fast_exp2(sa[mb][2]), e3 = fast_exp2(sa[mb][3]);
      float e4 = fast_exp2(sb[mb][0]), e5 = fast_exp2(sb[mb][1]);
      float e6 = fast_exp2(sb[mb][2]), e7 = fast_exp2(sb[mb][3]);
      lsum[mb] += ((e0 + e1) + (e2 + e3)) + ((e4 + e5) + (e6 + e7));
      pf[mb][0] = (bf16_t)e0; pf[mb][1] = (bf16_t)e1;
      pf[mb][2] = (bf16_t)e2; pf[mb][3] = (bf16_t)e3;
      pf[mb][4] = (bf16_t)e4; pf[mb][5] = (bf16_t)e5;
      pf[mb][6] = (bf16_t)e6; pf[mb][7] = (bf16_t)e7;
    }
#pragma unroll
    for (int nb = 0; nb < 4; ++nb) {
      cacc[0][nb] = __builtin_amdgcn_mfma_f32_16x16x32_bf16(av[nb], pf[0], cacc[0][nb], 0, 0, 0);
      cacc[1][nb] = __builtin_amdgcn_mfma_f32_16x16x32_bf16(av[nb], pf[1], cacc[1][nb], 0, 0, 0);
    }
  };

  if (clean) {
    // ---- branch-free hot path: one-chunk-ahead QK pipeline ----
    auto compute_clean = [&](const bf16_t* __restrict__ lKb,
                             const bf16_t* __restrict__ lVb) {
      bf16x8 kf[2][2][2];   // [parity][cc][half]
      bf16x8 av[2][4];      // [parity][nb]
      // preload chunk 0 operands
#pragma unroll
      for (int cc = 0; cc < 2; ++cc) {
        const int ko = ((cc * 4 + quad) ^ (l16 & 7)) * 8;
        kf[0][cc][0] = *(const bf16x8*)(lKb + (l16) * 64 + ko);
        kf[0][cc][1] = *(const bf16x8*)(lKb + (16 + l16) * 64 + ko);
      }
#pragma unroll
      for (int nb = 0; nb < 4; ++nb)
        av[0][nb] = *(const bf16x8*)(lVb + (nb * 16 + l16) * 128
                                     + ((quad ^ (l16 & 7)) * 8));
      // QK for chunk 0
      floatx4 sa_c[2], sb_c[2];
      sa_c[0] = vzero; sa_c[1] = vzero; sb_c[0] = vzero; sb_c[1] = vzero;
#pragma unroll
      for (int cc = 0; cc < 2; ++cc)
#pragma unroll
        for (int mb = 0; mb < 2; ++mb) {
          sa_c[mb] = __builtin_amdgcn_mfma_f32_16x16x32_bf16(kf[0][cc][0], qa[mb][cc], sa_c[mb], 0, 0, 0);
          sb_c[mb] = __builtin_amdgcn_mfma_f32_16x16x32_bf16(kf[0][cc][1], qa[mb][cc], sb_c[mb], 0, 0, 0);
        }
#pragma unroll
      for (int c = 0; c < 4; ++c) {
        const int buf = c & 1, nbuf = buf ^ 1;
        if (c < 3) {  // issue next-chunk ds_reads; latency hides under exp below
#pragma unroll
          for (int cc = 0; cc < 2; ++cc) {
            const int ko = ((cc * 4 + quad) ^ (l16 & 7)) * 8;
            kf[nbuf][cc][0] = *(const bf16x8*)(lKb + ((c + 1) * 32 + l16) * 64 + ko);
            kf[nbuf][cc][1] = *(const bf16x8*)(lKb + ((c + 1) * 32 + 16 + l16) * 64 + ko);
          }
          const int chn = ((c + 1) * 4 + quad) ^ (l16 & 7);
#pragma unroll
          for (int nb = 0; nb < 4; ++nb)
            av[nbuf][nb] = *(const bf16x8*)(lVb + (nb * 16 + l16) * 128 + chn * 8);
        }
        // exp of current chunk (VALU; covers the ds latency above)
        bf16x8 pf[2];
#pragma unroll
        for (int mb = 0; mb < 2; ++mb) {
          float e0 = fast_exp2(sa_c[mb][0]), e1 = fast_exp2(sa_c[mb][1]);
          float e2 = fast_exp2(sa_c[mb][2]), e3 = fast_exp2(sa_c[mb][3]);
          float e4 = fast_exp2(sb_c[mb][0]), e5 = fast_exp2(sb_c[mb][1]);
          float e6 = fast_exp2(sb_c[mb][2]), e7 = fast_exp2(sb_c[mb][3]);
          lsum[mb] += ((e0 + e1) + (e2 + e3)) + ((e4 + e5) + (e6 + e7));
          pf[mb][0] = (bf16_t)e0; pf[mb][1] = (bf16_t)e1;
          pf[mb][2] = (bf16_t)e2; pf[mb][3] = (bf16_t)e3;
          pf[mb][4] = (bf16_t)e4; pf[mb][5] = (bf16_t)e5;
          pf[mb][6] = (bf16_t)e6; pf[mb][7] = (bf16_t)e7;
        }
        // QK for next chunk (MFMA pipe fills while pf was packing)
        floatx4 sa_n[2], sb_n[2];
        sa_n[0] = vzero; sa_n[1] = vzero; sb_n[0] = vzero; sb_n[1] = vzero;
        if (c < 3) {
#pragma unroll
          for (int cc = 0; cc < 2; ++cc)
#pragma unroll
            for (int mb = 0; mb < 2; ++mb) {
              sa_n[mb] = __builtin_amdgcn_mfma_f32_16x16x32_bf16(kf[nbuf][cc][0], qa[mb][cc], sa_n[mb], 0, 0, 0);
              sb_n[mb] = __builtin_amdgcn_mfma_f32_16x16x32_bf16(kf[nbuf][cc][1], qa[mb][cc], sb_n[mb], 0, 0, 0);
            }
        }
        // PV of current chunk
#pragma unroll
        for (int nb = 0; nb < 4; ++nb) {
          cacc[0][nb] = __builtin_amdgcn_mfma_f32_16x16x32_bf16(av[buf][nb], pf[0], cacc[0][nb], 0, 0, 0);
          cacc[1][nb] = __builtin_amdgcn_mfma_f32_16x16x32_bf16(av[buf][nb], pf[1], cacc[1][nb], 0, 0, 0);
        }
#pragma unroll
        for (int mb = 0; mb < 2; ++mb) { sa_c[mb] = sa_n[mb]; sb_c[mb] = sb_n[mb]; }
      }
    };

    stage(0, 0);
#pragma unroll 1
    for (int s0 = 0; s0 < SS; s0 += 256) {
      __syncthreads();                  // drains stage->buf0; buf1 readers done
      stage(1, s0 + 128);
      compute_clean(lK[0], lV[0]);
      __syncthreads();                  // drains stage->buf1; buf0 readers done
      if (s0 + 256 < SS) stage(0, s0 + 256);
      compute_clean(lK[1], lV[1]);
    }
  } else {
    // ---- masked fallback: exact R1 loop ----
    auto compute_masked = [&](const bf16_t* __restrict__ lKb,
                              const bf16_t* __restrict__ lVb, int s0) {
#pragma unroll
      for (int c = 0; c < 4; ++c) {
        floatx4 sa[2], sb[2];
        sa[0] = vzero; sa[1] = vzero; sb[0] = vzero; sb[1] = vzero;
#pragma unroll
        for (int cc = 0; cc < 2; ++cc) {
          const int ko = ((cc * 4 + quad) ^ (l16 & 7)) * 8;
          bf16x8 kf0 = *(const bf16x8*)(lKb + (c * 32 + l16) * 64 + ko);
          bf16x8 kf1 = *(const bf16x8*)(lKb + (c * 32 + 16 + l16) * 64 + ko);
#pragma unroll
          for (int mb = 0; mb < 2; ++mb) {
            sa[mb] = __builtin_amdgcn_mfma_f32_16x16x32_bf16(kf0, qa[mb][cc], sa[mb], 0, 0, 0);
            sb[mb] = __builtin_amdgcn_mfma_f32_16x16x32_bf16(kf1, qa[mb][cc], sb[mb], 0, 0, 0);
          }
        }
        const int4 m0 = *(const int4*)(maskb + s0 + c * 32 + quad * 4);
        const int4 m1 = *(const int4*)(maskb + s0 + c * 32 + 16 + quad * 4);
#pragma unroll
        for (int mb = 0; mb < 2; ++mb) {
          if (m0.x == 0) sa[mb][0] = -1e30f;
          if (m0.y == 0) sa[mb][1] = -1e30f;
          if (m0.z == 0) sa[mb][2] = -1e30f;
          if (m0.w == 0) sa[mb][3] = -1e30f;
          if (m1.x == 0) sb[mb][0] = -1e30f;
          if (m1.y == 0) sb[mb][1] = -1e30f;
          if (m1.z == 0) sb[mb][2] = -1e30f;
          if (m1.w == 0) sb[mb][3] = -1e30f;
        }
        const int ch = (c * 4 + quad) ^ (l16 & 7);
        bf16x8 av[4];
#pragma unroll
        for (int nb = 0; nb < 4; ++nb)
          av[nb] = *(const bf16x8*)(lVb + (nb * 16 + l16) * 128 + ch * 8);
        exp_pv(sa, sb, av);
      }
    };

    stage(0, 0);
#pragma unroll 1
    for (int s0 = 0; s0 < SS; s0 += 256) {
      __syncthreads();
      stage(1, s0 + 128);
      compute_masked(lK[0], lV[0], s0);
      __syncthreads();
      if (s0 + 256 < SS) stage(0, s0 + 256);
      compute_masked(lK[1], lV[1], s0 + 128);
    }
  }

  // ---- epilogue: O^T cols=qrow=l16, rows=dh=nb*16+quad*4+r -> 8B stores ----
#pragma unroll
  for (int mb = 0; mb < 2; ++mb) {
    float tot = lsum[mb];
    tot += __shfl_xor(tot, 16);
    tot += __shfl_xor(tot, 32);       // sum across the 4 quad-lanes of this qrow
    const float inv = 1.0f / tot;
    const size_t qrow = qrow0 + wave * 32 + mb * 16 + l16;
#pragma unroll
    for (int nb = 0; nb < 4; ++nb) {
      bf16x4 o = {(bf16_t)(cacc[mb][nb][0] * inv), (bf16_t)(cacc[mb][nb][1] * inv),
                  (bf16_t)(cacc[mb][nb][2] * inv), (bf16_t)(cacc[mb][nb][3] * inv)};
      *(bf16x4*)(ctx + qrow * DM + h * DHD + nb * 16 + quad * 4) = o;
    }
  }
}

// ---------------------------------------------------------------------------
extern "C" void kernel_launch(void* const* d_in, const int* in_sizes, int n_in,
                              void* d_out, int out_size, void* d_ws, size_t ws_size,
                              hipStream_t stream)
{
  (void)in_sizes; (void)n_in; (void)out_size; (void)ws_size;
  const float* reaction = (const float*)d_in[0];
  const int*   mask     = (const int*)d_in[1];
  const float* Wq = (const float*)d_in[2];
  const float* Wk = (const float*)d_in[3];
  const float* Wv = (const float*)d_in[4];
  const float* Wo = (const float*)d_in[5];
  const float* bo = (const float*)d_in[6];
  const float* W1 = (const float*)d_in[7];
  const float* b1 = (const float*)d_in[8];
  const float* W2 = (const float*)d_in[9];
  const float* b2 = (const float*)d_in[10];
  const float* g_sa = (const float*)d_in[11];
  const float* b_sa = (const float*)d_in[12];
  const float* g_ff = (const float*)d_in[13];
  const float* b_ff = (const float*)d_in[14];
  float* out = (float*)d_out;

  char* ws = (char*)d_ws;
  size_t off = 0;
  auto take = [&](size_t bytes) -> char* {
    char* p = ws + off;
    off += (bytes + 255) & ~(size_t)255;
    return p;
  };

  bf16_t* xln   = (bf16_t*)take((size_t)MT * DM * 2);       // LN1 out; reused as LN2 out
  bf16_t* WqkvT = (bf16_t*)take((size_t)3 * DM * DM * 2);   // [1536][512]
  bf16_t* WoT   = (bf16_t*)take((size_t)DM * DM * 2);
  bf16_t* W1T   = (bf16_t*)take((size_t)FFD * DM * 2);
  bf16_t* W2T   = (bf16_t*)take((size_t)DM * FFD * 2);
  bf16_t* qb    = (bf16_t*)take((size_t)MT * DM * 2);       // qb..ctx contiguous 32MB,
  bf16_t* kb    = (bf16_t*)take((size_t)MT * DM * 2);       // reused as FFN hidden h
  bf16_t* vtb   = (bf16_t*)take((size_t)DM * MT * 2);       // V transposed [D, M], sigma-permuted
  bf16_t* ctx   = (bf16_t*)take((size_t)MT * DM * 2);
  float*  x2    = (float*)take((size_t)MT * DM * 4);
  bf16_t* yb    = xln;
  bf16_t* hb    = qb;   // 8192*2048 bf16 = 32MB over qb/kb/vtb/ctx (all dead by then)

  // LN1 + all weight transposes in one dispatch (independent work)
  prep_ln<<<5120, 256, 0, stream>>>(reaction, g_sa, b_sa, xln,
                                    Wq, Wk, Wv, Wo, W1, W2, WqkvT, WoT, W1T, W2T);

  // Fused QKV projection (Q pre-scaled, V stored transposed + sigma-permuted)
  gemm_bt<4, 4, 5><<<dim3(64, 12), 256, 0, stream>>>(xln, WqkvT, MT, 3 * DM, DM,
                                                     nullptr, nullptr, qb, nullptr, kb, vtb, MT);

  attn_kernel<<<dim3(SS / 128, HN, BB), 256, 0, stream>>>(qb, kb, vtb, mask, ctx);

  // Output projection + GELU + residual -> x2 (fp32); K=512, grid-limited
  // 2 blocks/CU -> BK=128 halves barrier drains (48KB LDS, fits 2/CU)
  gemm_bt<4, 2, 2, 128><<<dim3(64, 8), 256, 0, stream>>>(ctx, WoT, MT, DM, DM,
                                                         bo, reaction, nullptr, x2, nullptr, nullptr, 0);

  ln_kernel<<<MT / 4, 256, 0, stream>>>(x2, g_ff, b_ff, yb);
  gemm_bt<4, 4, 3><<<dim3(64, 16), 256, 0, stream>>>(yb, W1T, MT, FFD, DM,
                                                     b1, nullptr, hb, nullptr, nullptr, nullptr, 0);
  // FFN2: K=2048, grid-limited 2 blocks/CU -> BK=128 halves barrier drains
  gemm_bt<4, 2, 4, 128><<<dim3(64, 8), 256, 0, stream>>>(hb, W2T, MT, DM, FFD,
                                                         b2, x2, nullptr, out, nullptr, nullptr, 0);
}

// Round 11
// 263.837 us; speedup vs baseline: 1.0368x; 1.0368x over previous
//
#include <hip/hip_runtime.h>
#include <hip/hip_bf16.h>
#include <math.h>

#define HN 8
#define DM 512
#define DHD 64
#define FFD 2048
#define BB 2
#define SS 4096
#define MT (BB*SS)   // 8192 token rows

typedef __bf16 bf16_t;
typedef __bf16 bf16x8 __attribute__((ext_vector_type(8)));
typedef __bf16 bf16x4 __attribute__((ext_vector_type(4)));
typedef float  floatx4 __attribute__((ext_vector_type(4)));

// Async global->LDS. NOTE (m104/m108): LDS dest is wave-uniform base + lane*16;
// all swizzling must be applied on the GLOBAL SOURCE side, LDS dest stays linear.
__device__ __forceinline__ void async_copy16(const bf16_t* g, bf16_t* l) {
  __builtin_amdgcn_global_load_lds((const __attribute__((address_space(1))) void*)g,
                                   (__attribute__((address_space(3))) void*)l,
                                   16, 0, 0);
}

#if __has_builtin(__builtin_amdgcn_exp2f)
__device__ __forceinline__ float fast_exp2(float x) { return __builtin_amdgcn_exp2f(x); }
#else
__device__ __forceinline__ float fast_exp2(float x) { return __expf(x * 0.69314718056f); }
#endif

// tanh-form GELU via exp2 (max |err| vs exact erf-GELU ~3e-3, ~10 VALU ops)
__device__ __forceinline__ float gelu_f(float x) {
  float y = 0.7978845608f * (x + 0.044715f * x * x * x);
  float e = fast_exp2(y * 2.885390082f);   // exp(2y)
  float th = 1.0f - 2.0f / (e + 1.0f);
  return 0.5f * x * (1.0f + th);
}

// ---- Merged LN1 + weight-prep: independent prologue work, one dispatch ----
// blocks 0..2047: LayerNorm rows (4/block); blocks 2048..5119: transposes.
__global__ __launch_bounds__(256)
void prep_ln(const float* __restrict__ x, const float* __restrict__ g,
             const float* __restrict__ be, bf16_t* __restrict__ out,
             const float* __restrict__ Wq, const float* __restrict__ Wk,
             const float* __restrict__ Wv, const float* __restrict__ Wo,
             const float* __restrict__ W1, const float* __restrict__ W2,
             bf16_t* __restrict__ WqkvT, bf16_t* __restrict__ WoT,
             bf16_t* __restrict__ W1T, bf16_t* __restrict__ W2T)
{
  __shared__ float tile[32][33];
  if (blockIdx.x < 2048) {
    const int wave = threadIdx.x >> 6, lane = threadIdx.x & 63;
    const int row = blockIdx.x * 4 + wave;
    const float* xr = x + (size_t)row * DM + lane * 8;
    float4 a = *(const float4*)xr;
    float4 c = *(const float4*)(xr + 4);
    float s  = (a.x + a.y) + (a.z + a.w) + (c.x + c.y) + (c.z + c.w);
    float s2 = (a.x*a.x + a.y*a.y) + (a.z*a.z + a.w*a.w)
             + (c.x*c.x + c.y*c.y) + (c.z*c.z + c.w*c.w);
#pragma unroll
    for (int o = 1; o < 64; o <<= 1) { s += __shfl_xor(s, o); s2 += __shfl_xor(s2, o); }
    const float mu = s * (1.0f / DM);
    const float rv = rsqrtf(s2 * (1.0f / DM) - mu * mu + 1e-5f);
    float4 g0 = *(const float4*)(g + lane * 8);
    float4 g1 = *(const float4*)(g + lane * 8 + 4);
    float4 b0 = *(const float4*)(be + lane * 8);
    float4 b1 = *(const float4*)(be + lane * 8 + 4);
    bf16x8 o8;
    o8[0] = (bf16_t)((a.x - mu) * rv * g0.x + b0.x);
    o8[1] = (bf16_t)((a.y - mu) * rv * g0.y + b0.y);
    o8[2] = (bf16_t)((a.z - mu) * rv * g0.z + b0.z);
    o8[3] = (bf16_t)((a.w - mu) * rv * g0.w + b0.w);
    o8[4] = (bf16_t)((c.x - mu) * rv * g1.x + b1.x);
    o8[5] = (bf16_t)((c.y - mu) * rv * g1.y + b1.y);
    o8[6] = (bf16_t)((c.z - mu) * rv * g1.z + b1.z);
    o8[7] = (bf16_t)((c.w - mu) * rv * g1.w + b1.w);
    *(bf16x8*)(out + (size_t)row * DM + lane * 8) = o8;
    return;
  }
  const int bid = blockIdx.x - 2048;
  const float* src; bf16_t* dst; int Kd, Nd, n0, k0;
  if (bid < 768) {
    int seg = bid >> 8, t = bid & 255;
    src = (seg == 0) ? Wq : (seg == 1) ? Wk : Wv;
    dst = WqkvT + (size_t)seg * 512 * 512;
    Kd = 512; Nd = 512; n0 = (t & 15) * 32; k0 = (t >> 4) * 32;
  } else if (bid < 1024) {
    int t = bid - 768; src = Wo; dst = WoT;
    Kd = 512; Nd = 512; n0 = (t & 15) * 32; k0 = (t >> 4) * 32;
  } else if (bid < 2048) {
    int t = bid - 1024; src = W1; dst = W1T;
    Kd = 512; Nd = 2048; n0 = (t & 63) * 32; k0 = (t >> 6) * 32;
  } else {
    int t = bid - 2048; src = W2; dst = W2T;
    Kd = 2048; Nd = 512; n0 = (t & 15) * 32; k0 = (t >> 4) * 32;
  }
  const int tx = threadIdx.x & 31, ty = threadIdx.x >> 5;
#pragma unroll
  for (int i = 0; i < 32; i += 8)
    tile[ty + i][tx] = src[(size_t)(k0 + ty + i) * Nd + n0 + tx];
  __syncthreads();
#pragma unroll
  for (int i = 0; i < 32; i += 8)
    dst[(size_t)(n0 + ty + i) * Kd + k0 + tx] = (bf16_t)tile[tx][ty + i];
}

// ------- LayerNorm: fp32 in -> bf16 out; 1 wave per row, 4 rows/block -------
__global__ __launch_bounds__(256)
void ln_kernel(const float* __restrict__ x, const float* __restrict__ g,
               const float* __restrict__ be, bf16_t* __restrict__ out)
{
  const int wave = threadIdx.x >> 6, lane = threadIdx.x & 63;
  const int row = blockIdx.x * 4 + wave;
  const float* xr = x + (size_t)row * DM + lane * 8;
  float4 a = *(const float4*)xr;
  float4 c = *(const float4*)(xr + 4);
  float s  = (a.x + a.y) + (a.z + a.w) + (c.x + c.y) + (c.z + c.w);
  float s2 = (a.x*a.x + a.y*a.y) + (a.z*a.z + a.w*a.w)
           + (c.x*c.x + c.y*c.y) + (c.z*c.z + c.w*c.w);
#pragma unroll
  for (int o = 1; o < 64; o <<= 1) { s += __shfl_xor(s, o); s2 += __shfl_xor(s2, o); }
  const float mu = s * (1.0f / DM);
  const float rv = rsqrtf(s2 * (1.0f / DM) - mu * mu + 1e-5f);
  float4 g0 = *(const float4*)(g + lane * 8);
  float4 g1 = *(const float4*)(g + lane * 8 + 4);
  float4 b0 = *(const float4*)(be + lane * 8);
  float4 b1 = *(const float4*)(be + lane * 8 + 4);
  bf16x8 o8;
  o8[0] = (bf16_t)((a.x - mu) * rv * g0.x + b0.x);
  o8[1] = (bf16_t)((a.y - mu) * rv * g0.y + b0.y);
  o8[2] = (bf16_t)((a.z - mu) * rv * g0.z + b0.z);
  o8[3] = (bf16_t)((a.w - mu) * rv * g0.w + b0.w);
  o8[4] = (bf16_t)((c.x - mu) * rv * g1.x + b1.x);
  o8[5] = (bf16_t)((c.y - mu) * rv * g1.y + b1.y);
  o8[6] = (bf16_t)((c.z - mu) * rv * g1.z + b1.z);
  o8[7] = (bf16_t)((c.w - mu) * rv * g1.w + b1.w);
  *(bf16x8*)(out + (size_t)row * DM + lane * 8) = o8;
}

// ---------------- GEMM: C[M,N] = A[M,K] * Bt[N,K]^T, bf16 MFMA --------------
// R1 structure (single-buffer, already one scheduling region -> pipelining
// variants were null R3/R6). BKT=128 ONLY where the grid limits occupancy to
// 2 blocks/CU AND LDS at BK=128 fits twice (<=80KB/block): FFN2 (K=2048,
// proven R9) and Wo (K=512, (4,2)=48KB, tracked R10). QKV/FFN1 (4,4) would
// need 64KB -> m132 occupancy cliff -> stay BK=64.
// Staging map: flat chunk f covers row f/CH, chunk f%CH (CH=BKT/8); source
// col XOR'd by (row & (CH-1)); read chunk (c*4+quad)^(l16&(CH-1)) -> 2-way
// bank aliasing max (free, m136).
// EPI: 2 = f32 gelu(acc+bias)+res; 3 = bf16 gelu(acc+bias); 4 = f32 acc+bias+res
//      5 = fused-QKV epilogue (q scaled, k row-major, v transposed+sigma-permuted)
template <int MI, int NJ, int EPI, int BKT = 64>
__global__ __launch_bounds__(256)
void gemm_bt(const bf16_t* __restrict__ A, const bf16_t* __restrict__ Bt,
             const int M, const int N, const int K,
             const float* __restrict__ bias, const float* __restrict__ res,
             bf16_t* __restrict__ outb, float* __restrict__ outf,
             bf16_t* __restrict__ out2, bf16_t* __restrict__ out3, const int ldt)
{
  constexpr int MTILE = 32 * MI, NTILE = 32 * NJ;
  constexpr int CH = BKT / 8;                 // 16B chunks per row
  constexpr int ACOPY = MTILE * BKT / 2048;   // copy16 per thread per K-step
  constexpr int BCOPY = NTILE * BKT / 2048;
  __shared__ __align__(16) bf16_t lA[MTILE * BKT];
  __shared__ __align__(16) bf16_t lB[NTILE * BKT];
  const int tid = threadIdx.x;
  const int wave = tid >> 6, lane = tid & 63;
  const int wm = wave & 1, wn = wave >> 1;
  const int quad = lane >> 4, l16 = lane & 15;

  int srA[ACOPY > BCOPY ? ACOPY : BCOPY], scA[ACOPY > BCOPY ? ACOPY : BCOPY];
#pragma unroll
  for (int i = 0; i < (ACOPY > BCOPY ? ACOPY : BCOPY); ++i) {
    int flat = tid + 256 * i;
    int r = flat / CH, ch = flat % CH;
    srA[i] = r;
    scA[i] = (ch ^ (r & (CH - 1))) * 8;  // source-side swizzle, dest stays linear
  }
  const bf16_t* Ab = A + (size_t)(blockIdx.x * MTILE) * K;
  const bf16_t* Bb = Bt + (size_t)(blockIdx.y * NTILE) * K;

  const floatx4 vzero = {0.f, 0.f, 0.f, 0.f};
  floatx4 acc[MI][NJ];
#pragma unroll
  for (int i = 0; i < MI; ++i)
#pragma unroll
    for (int j = 0; j < NJ; ++j) acc[i][j] = vzero;

  for (int k0 = 0; k0 < K; k0 += BKT) {
    __syncthreads();
#pragma unroll
    for (int i = 0; i < ACOPY; ++i)
      async_copy16(Ab + (size_t)srA[i] * K + k0 + scA[i], lA + (tid + 256 * i) * 8);
#pragma unroll
    for (int i = 0; i < BCOPY; ++i)
      async_copy16(Bb + (size_t)srA[i] * K + k0 + scA[i], lB + (tid + 256 * i) * 8);
    __syncthreads();
#pragma unroll
    for (int c = 0; c < BKT / 32; ++c) {
      bf16x8 af[MI], bfv[NJ];
#pragma unroll
      for (int i = 0; i < MI; ++i)
        af[i] = *(const bf16x8*)(lA + (wm * 16 * MI + i * 16 + l16) * BKT
                                 + (((c * 4 + quad) ^ (l16 & (CH - 1))) * 8));
#pragma unroll
      for (int j = 0; j < NJ; ++j)
        bfv[j] = *(const bf16x8*)(lB + (wn * 16 * NJ + j * 16 + l16) * BKT
                                  + (((c * 4 + quad) ^ (l16 & (CH - 1))) * 8));
#pragma unroll
      for (int i = 0; i < MI; ++i)
#pragma unroll
        for (int j = 0; j < NJ; ++j)
          acc[i][j] = __builtin_amdgcn_mfma_f32_16x16x32_bf16(af[i], bfv[j], acc[i][j], 0, 0, 0);
    }
  }

  const int m00 = blockIdx.x * MTILE + wm * 16 * MI;
  const int n00 = blockIdx.y * NTILE + wn * 16 * NJ;
#pragma unroll
  for (int i = 0; i < MI; ++i) {
#pragma unroll
    for (int j = 0; j < NJ; ++j) {
      const int m0 = m00 + i * 16 + quad * 4;     // C/D: row=quad*4+reg, col=l16
      const int n  = n00 + j * 16 + l16;
      floatx4 v = acc[i][j];
      if (EPI == 2) {
        const float bb = bias[n];
#pragma unroll
        for (int r = 0; r < 4; ++r)
          outf[(size_t)(m0 + r) * N + n] = gelu_f(v[r] + bb) + res[(size_t)(m0 + r) * N + n];
      } else if (EPI == 3) {
        const float bb = bias[n];
#pragma unroll
        for (int r = 0; r < 4; ++r)
          outb[(size_t)(m0 + r) * N + n] = (bf16_t)gelu_f(v[r] + bb);
      } else if (EPI == 4) {
        const float bb = bias[n];
#pragma unroll
        for (int r = 0; r < 4; ++r)
          outf[(size_t)(m0 + r) * N + n] = v[r] + bb + res[(size_t)(m0 + r) * N + n];
      } else { // EPI 5: fused QKV
        const int seg = blockIdx.y >> 2;          // 0=Q 1=K 2=V (uniform per block)
        if (seg == 0) {
          // fold softmax scale (1/sqrt(64) * log2(e)) into Q, exact in fp32
#pragma unroll
          for (int r = 0; r < 4; ++r)
            outb[(size_t)(m0 + r) * 512 + n] = (bf16_t)(v[r] * 0.180336879f);
        } else if (seg == 1) {
#pragma unroll
          for (int r = 0; r < 4; ++r) out2[(size_t)(m0 + r) * 512 + (n - 512)] = (bf16_t)v[r];
        } else {
          // sigma-permute keys within 32-groups so attn PV A-frags are contiguous:
          // stored p = (o&3) + ((o>>2)&3)*8 + ((o>>4)&1)*4, o = m0&31 (mult of 4)
          const int o = m0 & 31;
          const int p0 = (m0 & ~31) + ((o >> 2) & 3) * 8 + ((o >> 4) << 2);
          bf16x4 pk = {(bf16_t)v[0], (bf16_t)v[1], (bf16_t)v[2], (bf16_t)v[3]};
          *(bf16x4*)(out3 + (size_t)(n - 1024) * ldt + p0) = pk;
        }
      }
    }
  }
}

// ---------------- Flash attention: Q-tile 128, 4 waves x 32 q-rows ----------
// FROZEN at R7/R9 (best measured: 77.8-78.3us, MfmaUtil ~37). Structure = R1
// (32 q-rows/wave, 128-key dbuf, 2/CU) + R7 scheduling:
// (1) clean/dirty loop specialization (branch-free hot loop);
// (2) next-chunk kf/av register prefetch (static 2-buffer) between QK and exp;
// (3) setprio(1) pins around MFMA clusters (R10 A/B: removing them + manual
//     QK-ahead pipeline REGRESSED 78->88us; this arrangement is the optimum).
// Key-split variants DEAD (R5 spill / R8 1-wave-per-SIMD at >256 regs).
// S^T = mfma(K-frag, Q-frag): C-layout rows=keys (quad*4+r), cols=qrow (l16).
// kappa-permuted K=32 PV: B-operand = concat of two exp2'd S^T C-regs;
// sigma-permuted V^T makes each PV A-frag one contiguous b128 read.
// XCD swizzle: blocks sharing one (b,h)'s K/V cluster onto one XCD's L2.
__global__ __launch_bounds__(256, 2)
void attn_kernel(const bf16_t* __restrict__ qm, const bf16_t* __restrict__ km,
                 const bf16_t* __restrict__ vtm, const int* __restrict__ mask,
                 bf16_t* __restrict__ ctx)
{
  // dispatch d -> XCD d%8 (round-robin); give XCD j the contiguous range
  // [j*64, j*64+64) = 2 full (b,h) groups. Bijective (512%8==0).
  const int flat = blockIdx.x + 32 * (blockIdx.y + 8 * blockIdx.z);
  const int swz = (flat & 7) * 64 + (flat >> 3);
  const int b = swz >> 8, h = (swz >> 5) & 7;
  const int q0 = (swz & 31) * 128;
  const int tid = threadIdx.x;
  const int wave = tid >> 6, lane = tid & 63;
  const int quad = lane >> 4, l16 = lane & 15;

  __shared__ __align__(16) bf16_t lK[2][128 * DHD];   // [buf][key][dh]        2x16 KB
  __shared__ __align__(16) bf16_t lV[2][DHD * 128];   // [buf][dh][stored key] 2x16 KB
  __shared__ int sclean[4];

  const int* maskb = mask + b * SS;

  // ---- block-level mask pre-check: umin over all 4096 ints ----
  unsigned um = 0xFFFFFFFFu;
#pragma unroll
  for (int i = 0; i < 4; ++i) {
    int4 m = *(const int4*)(maskb + tid * 16 + i * 4);
    um = min(um, min(min((unsigned)m.x, (unsigned)m.y), min((unsigned)m.z, (unsigned)m.w)));
  }
#pragma unroll
  for (int o = 1; o < 64; o <<= 1) um = min(um, (unsigned)__shfl_xor((int)um, o));
  if (lane == 0) sclean[wave] = (int)um;
  __syncthreads();
  const bool clean = (min(min((unsigned)sclean[0], (unsigned)sclean[1]),
                          min((unsigned)sclean[2], (unsigned)sclean[3])) != 0u);

  const size_t qrow0 = (size_t)b * SS + q0;
  // Q as B-operand frags (n=qrow=l16, k=dh=quad*8+t), pre-scaled by softmax factor
  bf16x8 qa[2][2];
#pragma unroll
  for (int mb = 0; mb < 2; ++mb)
#pragma unroll
    for (int cc = 0; cc < 2; ++cc)
      qa[mb][cc] = *(const bf16x8*)(qm + (qrow0 + wave * 32 + mb * 16 + l16) * DM
                                    + h * DHD + cc * 32 + quad * 8);

  const floatx4 vzero = {0.f, 0.f, 0.f, 0.f};
  floatx4 cacc[2][4];
  float lsum[2] = {0.f, 0.f};
#pragma unroll
  for (int mb = 0; mb < 2; ++mb)
#pragma unroll
    for (int nb = 0; nb < 4; ++nb) cacc[mb][nb] = vzero;

  const bf16_t* Kb = km + (size_t)b * SS * DM + h * DHD;
  const bf16_t* Vb = vtm + (size_t)(h * DHD) * MT + (size_t)b * SS;

  // ---- precomputed per-thread staging pointers (source-side XOR swizzle) ----
  const bf16_t* pk[4]; const bf16_t* pv[4];
#pragma unroll
  for (int i = 0; i < 4; ++i) {
    int p = tid + 256 * i;
    int key = p >> 3, cs = (p & 7) ^ (key & 7);
    pk[i] = Kb + (size_t)key * DM + cs * 8;
    int dh = p >> 4, cs2 = (p & 15) ^ (dh & 7);
    pv[i] = Vb + (size_t)dh * MT + cs2 * 8;
  }

  auto stage = [&](int buf, int s0) {
#pragma unroll
    for (int i = 0; i < 4; ++i) {
      int p8 = (tid + 256 * i) * 8;
      async_copy16(pk[i] + (size_t)s0 * DM, lK[buf] + p8);
      async_copy16(pv[i] + s0, lV[buf] + p8);
    }
  };

  // shared exp2->pf->PV tail for one chunk (math identical to R1)
  auto exp_pv = [&](floatx4 sa[2], floatx4 sb[2], const bf16x8 av[4]) {
    bf16x8 pf[2];
#pragma unroll
    for (int mb = 0; mb < 2; ++mb) {
      float e0 = fast_exp2(sa[mb][0]), e1 = fast_exp2(sa[mb][1]);
      float e2 = fast_exp2(sa[mb][2]), e3 = fast_exp2(sa[mb][3]);
      float e4 = fast_exp2(sb[mb][0]), e5 = fast_exp2(sb[mb][1]);
      float e6 = fast_exp2(sb[mb][2]), e7 = fast_exp2(sb[mb][3]);
      lsum[mb] += ((e0 + e1) + (e2 + e3)) + ((e4 + e5) + (e6 + e7));
      pf[mb][0] = (bf16_t)e0; pf[mb][1] = (bf16_t)e1;
      pf[mb][2] = (bf16_t)e2; pf[mb][3] = (bf16_t)e3;
      pf[mb][4] = (bf16_t)e4; pf[mb][5] = (bf16_t)e5;
      pf[mb][6] = (bf16_t)e6; pf[mb][7] = (bf16_t)e7;
    }
    __builtin_amdgcn_s_setprio(1);
#pragma unroll
    for (int nb = 0; nb < 4; ++nb) {
      cacc[0][nb] = __builtin_amdgcn_mfma_f32_16x16x32_bf16(av[nb], pf[0], cacc[0][nb], 0, 0, 0);
      cacc[1][nb] = __builtin_amdgcn_mfma_f32_16x16x32_bf16(av[nb], pf[1], cacc[1][nb], 0, 0, 0);
    }
    __builtin_amdgcn_s_setprio(0);
  };

  if (clean) {
    // ---- branch-free hot path with next-chunk register prefetch ----
    auto compute_clean = [&](const bf16_t* __restrict__ lKb,
                             const bf16_t* __restrict__ lVb) {
      bf16x8 kf[2][2][2];   // [c&1][cc][half]
      bf16x8 av[2][4];      // [c&1][nb]
      // preload chunk 0 operands
#pragma unroll
      for (int cc = 0; cc < 2; ++cc) {
        const int ko = ((cc * 4 + quad) ^ (l16 & 7)) * 8;
        kf[0][cc][0] = *(const bf16x8*)(lKb + (l16) * 64 + ko);
        kf[0][cc][1] = *(const bf16x8*)(lKb + (16 + l16) * 64 + ko);
      }
#pragma unroll
      for (int nb = 0; nb < 4; ++nb)
        av[0][nb] = *(const bf16x8*)(lVb + (nb * 16 + l16) * 128
                                     + ((quad ^ (l16 & 7)) * 8));
#pragma unroll
      for (int c = 0; c < 4; ++c) {
        const int buf = c & 1, nbuf = buf ^ 1;
        floatx4 sa[2], sb[2];
        sa[0] = vzero; sa[1] = vzero; sb[0] = vzero; sb[1] = vzero;
        __builtin_amdgcn_s_setprio(1);
#pragma unroll
        for (int cc = 0; cc < 2; ++cc)
#pragma unroll
          for (int mb = 0; mb < 2; ++mb) {
            sa[mb] = __builtin_amdgcn_mfma_f32_16x16x32_bf16(kf[buf][cc][0], qa[mb][cc], sa[mb], 0, 0, 0);
            sb[mb] = __builtin_amdgcn_mfma_f32_16x16x32_bf16(kf[buf][cc][1], qa[mb][cc], sb[mb], 0, 0, 0);
          }
        __builtin_amdgcn_s_setprio(0);
        if (c < 3) {  // prefetch chunk c+1 operands; latency hides under exp2
#pragma unroll
          for (int cc = 0; cc < 2; ++cc) {
            const int ko = (((cc * 4 + quad)) ^ (l16 & 7)) * 8;
            kf[nbuf][cc][0] = *(const bf16x8*)(lKb + ((c + 1) * 32 + l16) * 64 + ko);
            kf[nbuf][cc][1] = *(const bf16x8*)(lKb + ((c + 1) * 32 + 16 + l16) * 64 + ko);
          }
          const int chn = ((c + 1) * 4 + quad) ^ (l16 & 7);
#pragma unroll
          for (int nb = 0; nb < 4; ++nb)
            av[nbuf][nb] = *(const bf16x8*)(lVb + (nb * 16 + l16) * 128 + chn * 8);
        }
        exp_pv(sa, sb, av[buf]);
      }
    };

    stage(0, 0);
#pragma unroll 1
    for (int s0 = 0; s0 < SS; s0 += 256) {
      __syncthreads();                  // drains stage->buf0; buf1 readers done
      stage(1, s0 + 128);
      compute_clean(lK[0], lV[0]);
      __syncthreads();                  // drains stage->buf1; buf0 readers done
      if (s0 + 256 < SS) stage(0, s0 + 256);
      compute_clean(lK[1], lV[1]);
    }
  } else {
    // ---- masked fallback: exact R1 loop ----
    auto compute_masked = [&](const bf16_t* __restrict__ lKb,
                              const bf16_t* __restrict__ lVb, int s0) {
#pragma unroll
      for (int c = 0; c < 4; ++c) {
        floatx4 sa[2], sb[2];
        sa[0] = vzero; sa[1] = vzero; sb[0] = vzero; sb[1] = vzero;
#pragma unroll
        for (int cc = 0; cc < 2; ++cc) {
          const int ko = ((cc * 4 + quad) ^ (l16 & 7)) * 8;
          bf16x8 kf0 = *(const bf16x8*)(lKb + (c * 32 + l16) * 64 + ko);
          bf16x8 kf1 = *(const bf16x8*)(lKb + (c * 32 + 16 + l16) * 64 + ko);
          __builtin_amdgcn_s_setprio(1);
#pragma unroll
          for (int mb = 0; mb < 2; ++mb) {
            sa[mb] = __builtin_amdgcn_mfma_f32_16x16x32_bf16(kf0, qa[mb][cc], sa[mb], 0, 0, 0);
            sb[mb] = __builtin_amdgcn_mfma_f32_16x16x32_bf16(kf1, qa[mb][cc], sb[mb], 0, 0, 0);
          }
          __builtin_amdgcn_s_setprio(0);
        }
        const int4 m0 = *(const int4*)(maskb + s0 + c * 32 + quad * 4);
        const int4 m1 = *(const int4*)(maskb + s0 + c * 32 + 16 + quad * 4);
#pragma unroll
        for (int mb = 0; mb < 2; ++mb) {
          if (m0.x == 0) sa[mb][0] = -1e30f;
          if (m0.y == 0) sa[mb][1] = -1e30f;
          if (m0.z == 0) sa[mb][2] = -1e30f;
          if (m0.w == 0) sa[mb][3] = -1e30f;
          if (m1.x == 0) sb[mb][0] = -1e30f;
          if (m1.y == 0) sb[mb][1] = -1e30f;
          if (m1.z == 0) sb[mb][2] = -1e30f;
          if (m1.w == 0) sb[mb][3] = -1e30f;
        }
        const int ch = (c * 4 + quad) ^ (l16 & 7);
        bf16x8 av[4];
#pragma unroll
        for (int nb = 0; nb < 4; ++nb)
          av[nb] = *(const bf16x8*)(lVb + (nb * 16 + l16) * 128 + ch * 8);
        exp_pv(sa, sb, av);
      }
    };

    stage(0, 0);
#pragma unroll 1
    for (int s0 = 0; s0 < SS; s0 += 256) {
      __syncthreads();
      stage(1, s0 + 128);
      compute_masked(lK[0], lV[0], s0);
      __syncthreads();
      if (s0 + 256 < SS) stage(0, s0 + 256);
      compute_masked(lK[1], lV[1], s0 + 128);
    }
  }

  // ---- epilogue: O^T cols=qrow=l16, rows=dh=nb*16+quad*4+r -> 8B stores ----
#pragma unroll
  for (int mb = 0; mb < 2; ++mb) {
    float tot = lsum[mb];
    tot += __shfl_xor(tot, 16);
    tot += __shfl_xor(tot, 32);       // sum across the 4 quad-lanes of this qrow
    const float inv = 1.0f / tot;
    const size_t qrow = qrow0 + wave * 32 + mb * 16 + l16;
#pragma unroll
    for (int nb = 0; nb < 4; ++nb) {
      bf16x4 o = {(bf16_t)(cacc[mb][nb][0] * inv), (bf16_t)(cacc[mb][nb][1] * inv),
                  (bf16_t)(cacc[mb][nb][2] * inv), (bf16_t)(cacc[mb][nb][3] * inv)};
      *(bf16x4*)(ctx + qrow * DM + h * DHD + nb * 16 + quad * 4) = o;
    }
  }
}

// ---------------------------------------------------------------------------
extern "C" void kernel_launch(void* const* d_in, const int* in_sizes, int n_in,
                              void* d_out, int out_size, void* d_ws, size_t ws_size,
                              hipStream_t stream)
{
  (void)in_sizes; (void)n_in; (void)out_size; (void)ws_size;
  const float* reaction = (const float*)d_in[0];
  const int*   mask     = (const int*)d_in[1];
  const float* Wq = (const float*)d_in[2];
  const float* Wk = (const float*)d_in[3];
  const float* Wv = (const float*)d_in[4];
  const float* Wo = (const float*)d_in[5];
  const float* bo = (const float*)d_in[6];
  const float* W1 = (const float*)d_in[7];
  const float* b1 = (const float*)d_in[8];
  const float* W2 = (const float*)d_in[9];
  const float* b2 = (const float*)d_in[10];
  const float* g_sa = (const float*)d_in[11];
  const float* b_sa = (const float*)d_in[12];
  const float* g_ff = (const float*)d_in[13];
  const float* b_ff = (const float*)d_in[14];
  float* out = (float*)d_out;

  char* ws = (char*)d_ws;
  size_t off = 0;
  auto take = [&](size_t bytes) -> char* {
    char* p = ws + off;
    off += (bytes + 255) & ~(size_t)255;
    return p;
  };

  bf16_t* xln   = (bf16_t*)take((size_t)MT * DM * 2);       // LN1 out; reused as LN2 out
  bf16_t* WqkvT = (bf16_t*)take((size_t)3 * DM * DM * 2);   // [1536][512]
  bf16_t* WoT   = (bf16_t*)take((size_t)DM * DM * 2);
  bf16_t* W1T   = (bf16_t*)take((size_t)FFD * DM * 2);
  bf16_t* W2T   = (bf16_t*)take((size_t)DM * FFD * 2);
  bf16_t* qb    = (bf16_t*)take((size_t)MT * DM * 2);       // qb..ctx contiguous 32MB,
  bf16_t* kb    = (bf16_t*)take((size_t)MT * DM * 2);       // reused as FFN hidden h
  bf16_t* vtb   = (bf16_t*)take((size_t)DM * MT * 2);       // V transposed [D, M], sigma-permuted
  bf16_t* ctx   = (bf16_t*)take((size_t)MT * DM * 2);
  float*  x2    = (float*)take((size_t)MT * DM * 4);
  bf16_t* yb    = xln;
  bf16_t* hb    = qb;   // 8192*2048 bf16 = 32MB over qb/kb/vtb/ctx (all dead by then)

  // LN1 + all weight transposes in one dispatch (independent work)
  prep_ln<<<5120, 256, 0, stream>>>(reaction, g_sa, b_sa, xln,
                                    Wq, Wk, Wv, Wo, W1, W2, WqkvT, WoT, W1T, W2T);

  // Fused QKV projection (Q pre-scaled, V stored transposed + sigma-permuted)
  gemm_bt<4, 4, 5><<<dim3(64, 12), 256, 0, stream>>>(xln, WqkvT, MT, 3 * DM, DM,
                                                     nullptr, nullptr, qb, nullptr, kb, vtb, MT);

  attn_kernel<<<dim3(SS / 128, HN, BB), 256, 0, stream>>>(qb, kb, vtb, mask, ctx);

  // Output projection + GELU + residual -> x2 (fp32); K=512, grid-limited
  // 2 blocks/CU -> BK=128 halves barrier drains (48KB LDS, fits 2/CU)
  gemm_bt<4, 2, 2, 128><<<dim3(64, 8), 256, 0, stream>>>(ctx, WoT, MT, DM, DM,
                                                         bo, reaction, nullptr, x2, nullptr, nullptr, 0);

  ln_kernel<<<MT / 4, 256, 0, stream>>>(x2, g_ff, b_ff, yb);
  gemm_bt<4, 4, 3><<<dim3(64, 16), 256, 0, stream>>>(yb, W1T, MT, FFD, DM,
                                                     b1, nullptr, hb, nullptr, nullptr, nullptr, 0);
  // FFN2: K=2048, grid-limited 2 blocks/CU -> BK=128 halves barrier drains
  gemm_bt<4, 2, 4, 128><<<dim3(64, 8), 256, 0, stream>>>(hb, W2T, MT, DM, FFD,
                                                         b2, x2, nullptr, out, nullptr, nullptr, 0);
}

// Round 12
// 256.623 us; speedup vs baseline: 1.0659x; 1.0281x over previous
//
#include <hip/hip_runtime.h>
#include <hip/hip_bf16.h>
#include <math.h>

#define HN 8
#define DM 512
#define DHD 64
#define FFD 2048
#define BB 2
#define SS 4096
#define MT (BB*SS)   // 8192 token rows

typedef __bf16 bf16_t;
typedef __bf16 bf16x8 __attribute__((ext_vector_type(8)));
typedef __bf16 bf16x4 __attribute__((ext_vector_type(4)));
typedef float  floatx4 __attribute__((ext_vector_type(4)));

// Async global->LDS. NOTE (m104/m108): LDS dest is wave-uniform base + lane*16;
// all swizzling must be applied on the GLOBAL SOURCE side, LDS dest stays linear.
__device__ __forceinline__ void async_copy16(const bf16_t* g, bf16_t* l) {
  __builtin_amdgcn_global_load_lds((const __attribute__((address_space(1))) void*)g,
                                   (__attribute__((address_space(3))) void*)l,
                                   16, 0, 0);
}

#if __has_builtin(__builtin_amdgcn_exp2f)
__device__ __forceinline__ float fast_exp2(float x) { return __builtin_amdgcn_exp2f(x); }
#else
__device__ __forceinline__ float fast_exp2(float x) { return __expf(x * 0.69314718056f); }
#endif

// tanh-form GELU via exp2 (max |err| vs exact erf-GELU ~3e-3, ~10 VALU ops)
__device__ __forceinline__ float gelu_f(float x) {
  float y = 0.7978845608f * (x + 0.044715f * x * x * x);
  float e = fast_exp2(y * 2.885390082f);   // exp(2y)
  float th = 1.0f - 2.0f / (e + 1.0f);
  return 0.5f * x * (1.0f + th);
}

// ---- Merged LN1 + weight-prep: independent prologue work, one dispatch ----
// blocks 0..2047: LayerNorm rows (4/block); blocks 2048..5119: transposes
// (R12: transpose source reads vectorized to float4 -> 1 load/thread, G13).
__global__ __launch_bounds__(256)
void prep_ln(const float* __restrict__ x, const float* __restrict__ g,
             const float* __restrict__ be, bf16_t* __restrict__ out,
             const float* __restrict__ Wq, const float* __restrict__ Wk,
             const float* __restrict__ Wv, const float* __restrict__ Wo,
             const float* __restrict__ W1, const float* __restrict__ W2,
             bf16_t* __restrict__ WqkvT, bf16_t* __restrict__ WoT,
             bf16_t* __restrict__ W1T, bf16_t* __restrict__ W2T)
{
  __shared__ float tile[32][33];
  if (blockIdx.x < 2048) {
    const int wave = threadIdx.x >> 6, lane = threadIdx.x & 63;
    const int row = blockIdx.x * 4 + wave;
    const float* xr = x + (size_t)row * DM + lane * 8;
    float4 a = *(const float4*)xr;
    float4 c = *(const float4*)(xr + 4);
    float s  = (a.x + a.y) + (a.z + a.w) + (c.x + c.y) + (c.z + c.w);
    float s2 = (a.x*a.x + a.y*a.y) + (a.z*a.z + a.w*a.w)
             + (c.x*c.x + c.y*c.y) + (c.z*c.z + c.w*c.w);
#pragma unroll
    for (int o = 1; o < 64; o <<= 1) { s += __shfl_xor(s, o); s2 += __shfl_xor(s2, o); }
    const float mu = s * (1.0f / DM);
    const float rv = rsqrtf(s2 * (1.0f / DM) - mu * mu + 1e-5f);
    float4 g0 = *(const float4*)(g + lane * 8);
    float4 g1 = *(const float4*)(g + lane * 8 + 4);
    float4 b0 = *(const float4*)(be + lane * 8);
    float4 b1 = *(const float4*)(be + lane * 8 + 4);
    bf16x8 o8;
    o8[0] = (bf16_t)((a.x - mu) * rv * g0.x + b0.x);
    o8[1] = (bf16_t)((a.y - mu) * rv * g0.y + b0.y);
    o8[2] = (bf16_t)((a.z - mu) * rv * g0.z + b0.z);
    o8[3] = (bf16_t)((a.w - mu) * rv * g0.w + b0.w);
    o8[4] = (bf16_t)((c.x - mu) * rv * g1.x + b1.x);
    o8[5] = (bf16_t)((c.y - mu) * rv * g1.y + b1.y);
    o8[6] = (bf16_t)((c.z - mu) * rv * g1.z + b1.z);
    o8[7] = (bf16_t)((c.w - mu) * rv * g1.w + b1.w);
    *(bf16x8*)(out + (size_t)row * DM + lane * 8) = o8;
    return;
  }
  const int bid = blockIdx.x - 2048;
  const float* src; bf16_t* dst; int Kd, Nd, n0, k0;
  if (bid < 768) {
    int seg = bid >> 8, t = bid & 255;
    src = (seg == 0) ? Wq : (seg == 1) ? Wk : Wv;
    dst = WqkvT + (size_t)seg * 512 * 512;
    Kd = 512; Nd = 512; n0 = (t & 15) * 32; k0 = (t >> 4) * 32;
  } else if (bid < 1024) {
    int t = bid - 768; src = Wo; dst = WoT;
    Kd = 512; Nd = 512; n0 = (t & 15) * 32; k0 = (t >> 4) * 32;
  } else if (bid < 2048) {
    int t = bid - 1024; src = W1; dst = W1T;
    Kd = 512; Nd = 2048; n0 = (t & 63) * 32; k0 = (t >> 6) * 32;
  } else {
    int t = bid - 2048; src = W2; dst = W2T;
    Kd = 2048; Nd = 512; n0 = (t & 15) * 32; k0 = (t >> 4) * 32;
  }
  // float4 read: thread (tyr, tx4) loads 4 consecutive floats of row k0+tyr
  const int tx4 = threadIdx.x & 7, tyr = threadIdx.x >> 3;
  float4 v4 = *(const float4*)(src + (size_t)(k0 + tyr) * Nd + n0 + tx4 * 4);
  tile[tyr][tx4 * 4 + 0] = v4.x;
  tile[tyr][tx4 * 4 + 1] = v4.y;
  tile[tyr][tx4 * 4 + 2] = v4.z;
  tile[tyr][tx4 * 4 + 3] = v4.w;
  __syncthreads();
  const int tx = threadIdx.x & 31, ty = threadIdx.x >> 5;
#pragma unroll
  for (int i = 0; i < 32; i += 8)
    dst[(size_t)(n0 + ty + i) * Kd + k0 + tx] = (bf16_t)tile[tx][ty + i];
}

// ------- LayerNorm: fp32 in -> bf16 out; 1 wave per row, 4 rows/block -------
__global__ __launch_bounds__(256)
void ln_kernel(const float* __restrict__ x, const float* __restrict__ g,
               const float* __restrict__ be, bf16_t* __restrict__ out)
{
  const int wave = threadIdx.x >> 6, lane = threadIdx.x & 63;
  const int row = blockIdx.x * 4 + wave;
  const float* xr = x + (size_t)row * DM + lane * 8;
  float4 a = *(const float4*)xr;
  float4 c = *(const float4*)(xr + 4);
  float s  = (a.x + a.y) + (a.z + a.w) + (c.x + c.y) + (c.z + c.w);
  float s2 = (a.x*a.x + a.y*a.y) + (a.z*a.z + a.w*a.w)
           + (c.x*c.x + c.y*c.y) + (c.z*c.z + c.w*c.w);
#pragma unroll
  for (int o = 1; o < 64; o <<= 1) { s += __shfl_xor(s, o); s2 += __shfl_xor(s2, o); }
  const float mu = s * (1.0f / DM);
  const float rv = rsqrtf(s2 * (1.0f / DM) - mu * mu + 1e-5f);
  float4 g0 = *(const float4*)(g + lane * 8);
  float4 g1 = *(const float4*)(g + lane * 8 + 4);
  float4 b0 = *(const float4*)(be + lane * 8);
  float4 b1 = *(const float4*)(be + lane * 8 + 4);
  bf16x8 o8;
  o8[0] = (bf16_t)((a.x - mu) * rv * g0.x + b0.x);
  o8[1] = (bf16_t)((a.y - mu) * rv * g0.y + b0.y);
  o8[2] = (bf16_t)((a.z - mu) * rv * g0.z + b0.z);
  o8[3] = (bf16_t)((a.w - mu) * rv * g0.w + b0.w);
  o8[4] = (bf16_t)((c.x - mu) * rv * g1.x + b1.x);
  o8[5] = (bf16_t)((c.y - mu) * rv * g1.y + b1.y);
  o8[6] = (bf16_t)((c.z - mu) * rv * g1.z + b1.z);
  o8[7] = (bf16_t)((c.w - mu) * rv * g1.w + b1.w);
  *(bf16x8*)(out + (size_t)row * DM + lane * 8) = o8;
}

// ---------------- GEMM: C[M,N] = A[M,K] * Bt[N,K]^T, bf16 MFMA --------------
// R1 structure (single-buffer; pipelining variants null R3/R6). Parameters:
//  BKT=128 only where grid-limited to 2 blocks/CU and dbl-LDS fits (FFN2 R9,
//  Wo R10). WV=8 (8 waves, 2x4 grid, NTILE=16*NJ*WV/2) only for FFN1:
//  grid (64,8)=512=2/CU x 8 waves = same 16 waves/CU as 4-wave at 4/CU, but
//  staging bytes/output -25% and total barrier events halved. QKV stays WV=4
//  (N=1536 -> 1.5 blocks/CU imbalance at 256-wide tiles).
// Staging map: flat chunk f covers row f/CH, chunk f%CH (CH=BKT/8); source
// col XOR'd by (row & (CH-1)); read chunk (c*4+quad)^(l16&(CH-1)) -> 2-way
// bank aliasing max (free, m136).
// EPI: 2 = f32 gelu(acc+bias)+res; 3 = bf16 gelu(acc+bias); 4 = f32 acc+bias+res
//      5 = fused-QKV epilogue (q scaled, k row-major, v transposed+sigma-permuted)
template <int MI, int NJ, int EPI, int BKT = 64, int WV = 4>
__global__ __launch_bounds__(64 * WV)
void gemm_bt(const bf16_t* __restrict__ A, const bf16_t* __restrict__ Bt,
             const int M, const int N, const int K,
             const float* __restrict__ bias, const float* __restrict__ res,
             bf16_t* __restrict__ outb, float* __restrict__ outf,
             bf16_t* __restrict__ out2, bf16_t* __restrict__ out3, const int ldt)
{
  constexpr int THREADS = 64 * WV;
  constexpr int WN = WV / 2;                  // wave-grid columns (2 x WN)
  constexpr int MTILE = 32 * MI, NTILE = 16 * NJ * WN;
  constexpr int CH = BKT / 8;                 // 16B chunks per row
  constexpr int ACOPY = MTILE * BKT / (8 * THREADS);
  constexpr int BCOPY = NTILE * BKT / (8 * THREADS);
  __shared__ __align__(16) bf16_t lA[MTILE * BKT];
  __shared__ __align__(16) bf16_t lB[NTILE * BKT];
  const int tid = threadIdx.x;
  const int wave = tid >> 6, lane = tid & 63;
  const int wm = wave & 1, wn = wave >> 1;
  const int quad = lane >> 4, l16 = lane & 15;

  int srA[ACOPY > BCOPY ? ACOPY : BCOPY], scA[ACOPY > BCOPY ? ACOPY : BCOPY];
#pragma unroll
  for (int i = 0; i < (ACOPY > BCOPY ? ACOPY : BCOPY); ++i) {
    int flat = tid + THREADS * i;
    int r = flat / CH, ch = flat % CH;
    srA[i] = r;
    scA[i] = (ch ^ (r & (CH - 1))) * 8;  // source-side swizzle, dest stays linear
  }
  const bf16_t* Ab = A + (size_t)(blockIdx.x * MTILE) * K;
  const bf16_t* Bb = Bt + (size_t)(blockIdx.y * NTILE) * K;

  const floatx4 vzero = {0.f, 0.f, 0.f, 0.f};
  floatx4 acc[MI][NJ];
#pragma unroll
  for (int i = 0; i < MI; ++i)
#pragma unroll
    for (int j = 0; j < NJ; ++j) acc[i][j] = vzero;

  for (int k0 = 0; k0 < K; k0 += BKT) {
    __syncthreads();
#pragma unroll
    for (int i = 0; i < ACOPY; ++i)
      async_copy16(Ab + (size_t)srA[i] * K + k0 + scA[i], lA + (tid + THREADS * i) * 8);
#pragma unroll
    for (int i = 0; i < BCOPY; ++i)
      async_copy16(Bb + (size_t)srA[i] * K + k0 + scA[i], lB + (tid + THREADS * i) * 8);
    __syncthreads();
#pragma unroll
    for (int c = 0; c < BKT / 32; ++c) {
      bf16x8 af[MI], bfv[NJ];
#pragma unroll
      for (int i = 0; i < MI; ++i)
        af[i] = *(const bf16x8*)(lA + (wm * 16 * MI + i * 16 + l16) * BKT
                                 + (((c * 4 + quad) ^ (l16 & (CH - 1))) * 8));
#pragma unroll
      for (int j = 0; j < NJ; ++j)
        bfv[j] = *(const bf16x8*)(lB + (wn * 16 * NJ + j * 16 + l16) * BKT
                                  + (((c * 4 + quad) ^ (l16 & (CH - 1))) * 8));
#pragma unroll
      for (int i = 0; i < MI; ++i)
#pragma unroll
        for (int j = 0; j < NJ; ++j)
          acc[i][j] = __builtin_amdgcn_mfma_f32_16x16x32_bf16(af[i], bfv[j], acc[i][j], 0, 0, 0);
    }
  }

  const int m00 = blockIdx.x * MTILE + wm * 16 * MI;
  const int n00 = blockIdx.y * NTILE + wn * 16 * NJ;
#pragma unroll
  for (int i = 0; i < MI; ++i) {
#pragma unroll
    for (int j = 0; j < NJ; ++j) {
      const int m0 = m00 + i * 16 + quad * 4;     // C/D: row=quad*4+reg, col=l16
      const int n  = n00 + j * 16 + l16;
      floatx4 v = acc[i][j];
      if (EPI == 2) {
        const float bb = bias[n];
#pragma unroll
        for (int r = 0; r < 4; ++r)
          outf[(size_t)(m0 + r) * N + n] = gelu_f(v[r] + bb) + res[(size_t)(m0 + r) * N + n];
      } else if (EPI == 3) {
        const float bb = bias[n];
#pragma unroll
        for (int r = 0; r < 4; ++r)
          outb[(size_t)(m0 + r) * N + n] = (bf16_t)gelu_f(v[r] + bb);
      } else if (EPI == 4) {
        const float bb = bias[n];
#pragma unroll
        for (int r = 0; r < 4; ++r)
          outf[(size_t)(m0 + r) * N + n] = v[r] + bb + res[(size_t)(m0 + r) * N + n];
      } else { // EPI 5: fused QKV
        const int seg = blockIdx.y >> 2;          // 0=Q 1=K 2=V (uniform per block)
        if (seg == 0) {
          // fold softmax scale (1/sqrt(64) * log2(e)) into Q, exact in fp32
#pragma unroll
          for (int r = 0; r < 4; ++r)
            outb[(size_t)(m0 + r) * 512 + n] = (bf16_t)(v[r] * 0.180336879f);
        } else if (seg == 1) {
#pragma unroll
          for (int r = 0; r < 4; ++r) out2[(size_t)(m0 + r) * 512 + (n - 512)] = (bf16_t)v[r];
        } else {
          // sigma-permute keys within 32-groups so attn PV A-frags are contiguous:
          // stored p = (o&3) + ((o>>2)&3)*8 + ((o>>4)&1)*4, o = m0&31 (mult of 4)
          const int o = m0 & 31;
          const int p0 = (m0 & ~31) + ((o >> 2) & 3) * 8 + ((o >> 4) << 2);
          bf16x4 pk = {(bf16_t)v[0], (bf16_t)v[1], (bf16_t)v[2], (bf16_t)v[3]};
          *(bf16x4*)(out3 + (size_t)(n - 1024) * ldt + p0) = pk;
        }
      }
    }
  }
}

// ---------------- Flash attention: Q-tile 128, 4 waves x 32 q-rows ----------
// FROZEN at R7/R9 (best measured: 77.8-78.3us fast-clock, MfmaUtil ~37).
// Structure = R1 (32 q-rows/wave, 128-key dbuf, 2/CU) + R7 scheduling:
// (1) clean/dirty loop specialization (branch-free hot loop);
// (2) next-chunk kf/av register prefetch (static 2-buffer) between QK and exp;
// (3) setprio(1) pins around MFMA clusters (R10 A/B: removing them + manual
//     QK-ahead pipeline REGRESSED 78->88us; this arrangement is the optimum).
// Key-split variants DEAD (R5 spill / R8 1-wave-per-SIMD at >256 regs).
// S^T = mfma(K-frag, Q-frag): C-layout rows=keys (quad*4+r), cols=qrow (l16).
// kappa-permuted K=32 PV: B-operand = concat of two exp2'd S^T C-regs;
// sigma-permuted V^T makes each PV A-frag one contiguous b128 read.
// XCD swizzle: blocks sharing one (b,h)'s K/V cluster onto one XCD's L2.
__global__ __launch_bounds__(256, 2)
void attn_kernel(const bf16_t* __restrict__ qm, const bf16_t* __restrict__ km,
                 const bf16_t* __restrict__ vtm, const int* __restrict__ mask,
                 bf16_t* __restrict__ ctx)
{
  // dispatch d -> XCD d%8 (round-robin); give XCD j the contiguous range
  // [j*64, j*64+64) = 2 full (b,h) groups. Bijective (512%8==0).
  const int flat = blockIdx.x + 32 * (blockIdx.y + 8 * blockIdx.z);
  const int swz = (flat & 7) * 64 + (flat >> 3);
  const int b = swz >> 8, h = (swz >> 5) & 7;
  const int q0 = (swz & 31) * 128;
  const int tid = threadIdx.x;
  const int wave = tid >> 6, lane = tid & 63;
  const int quad = lane >> 4, l16 = lane & 15;

  __shared__ __align__(16) bf16_t lK[2][128 * DHD];   // [buf][key][dh]        2x16 KB
  __shared__ __align__(16) bf16_t lV[2][DHD * 128];   // [buf][dh][stored key] 2x16 KB
  __shared__ int sclean[4];

  const int* maskb = mask + b * SS;

  // ---- block-level mask pre-check: umin over all 4096 ints ----
  unsigned um = 0xFFFFFFFFu;
#pragma unroll
  for (int i = 0; i < 4; ++i) {
    int4 m = *(const int4*)(maskb + tid * 16 + i * 4);
    um = min(um, min(min((unsigned)m.x, (unsigned)m.y), min((unsigned)m.z, (unsigned)m.w)));
  }
#pragma unroll
  for (int o = 1; o < 64; o <<= 1) um = min(um, (unsigned)__shfl_xor((int)um, o));
  if (lane == 0) sclean[wave] = (int)um;
  __syncthreads();
  const bool clean = (min(min((unsigned)sclean[0], (unsigned)sclean[1]),
                          min((unsigned)sclean[2], (unsigned)sclean[3])) != 0u);

  const size_t qrow0 = (size_t)b * SS + q0;
  // Q as B-operand frags (n=qrow=l16, k=dh=quad*8+t), pre-scaled by softmax factor
  bf16x8 qa[2][2];
#pragma unroll
  for (int mb = 0; mb < 2; ++mb)
#pragma unroll
    for (int cc = 0; cc < 2; ++cc)
      qa[mb][cc] = *(const bf16x8*)(qm + (qrow0 + wave * 32 + mb * 16 + l16) * DM
                                    + h * DHD + cc * 32 + quad * 8);

  const floatx4 vzero = {0.f, 0.f, 0.f, 0.f};
  floatx4 cacc[2][4];
  float lsum[2] = {0.f, 0.f};
#pragma unroll
  for (int mb = 0; mb < 2; ++mb)
#pragma unroll
    for (int nb = 0; nb < 4; ++nb) cacc[mb][nb] = vzero;

  const bf16_t* Kb = km + (size_t)b * SS * DM + h * DHD;
  const bf16_t* Vb = vtm + (size_t)(h * DHD) * MT + (size_t)b * SS;

  // ---- precomputed per-thread staging pointers (source-side XOR swizzle) ----
  const bf16_t* pk[4]; const bf16_t* pv[4];
#pragma unroll
  for (int i = 0; i < 4; ++i) {
    int p = tid + 256 * i;
    int key = p >> 3, cs = (p & 7) ^ (key & 7);
    pk[i] = Kb + (size_t)key * DM + cs * 8;
    int dh = p >> 4, cs2 = (p & 15) ^ (dh & 7);
    pv[i] = Vb + (size_t)dh * MT + cs2 * 8;
  }

  auto stage = [&](int buf, int s0) {
#pragma unroll
    for (int i = 0; i < 4; ++i) {
      int p8 = (tid + 256 * i) * 8;
      async_copy16(pk[i] + (size_t)s0 * DM, lK[buf] + p8);
      async_copy16(pv[i] + s0, lV[buf] + p8);
    }
  };

  // shared exp2->pf->PV tail for one chunk (math identical to R1)
  auto exp_pv = [&](floatx4 sa[2], floatx4 sb[2], const bf16x8 av[4]) {
    bf16x8 pf[2];
#pragma unroll
    for (int mb = 0; mb < 2; ++mb) {
      float e0 = fast_exp2(sa[mb][0]), e1 = fast_exp2(sa[mb][1]);
      float e2 = fast_exp2(sa[mb][2]), e3 = fast_exp2(sa[mb][3]);
      float e4 = fast_exp2(sb[mb][0]), e5 = fast_exp2(sb[mb][1]);
      float e6 = fast_exp2(sb[mb][2]), e7 = fast_exp2(sb[mb][3]);
      lsum[mb] += ((e0 + e1) + (e2 + e3)) + ((e4 + e5) + (e6 + e7));
      pf[mb][0] = (bf16_t)e0; pf[mb][1] = (bf16_t)e1;
      pf[mb][2] = (bf16_t)e2; pf[mb][3] = (bf16_t)e3;
      pf[mb][4] = (bf16_t)e4; pf[mb][5] = (bf16_t)e5;
      pf[mb][6] = (bf16_t)e6; pf[mb][7] = (bf16_t)e7;
    }
    __builtin_amdgcn_s_setprio(1);
#pragma unroll
    for (int nb = 0; nb < 4; ++nb) {
      cacc[0][nb] = __builtin_amdgcn_mfma_f32_16x16x32_bf16(av[nb], pf[0], cacc[0][nb], 0, 0, 0);
      cacc[1][nb] = __builtin_amdgcn_mfma_f32_16x16x32_bf16(av[nb], pf[1], cacc[1][nb], 0, 0, 0);
    }
    __builtin_amdgcn_s_setprio(0);
  };

  if (clean) {
    // ---- branch-free hot path with next-chunk register prefetch ----
    auto compute_clean = [&](const bf16_t* __restrict__ lKb,
                             const bf16_t* __restrict__ lVb) {
      bf16x8 kf[2][2][2];   // [c&1][cc][half]
      bf16x8 av[2][4];      // [c&1][nb]
      // preload chunk 0 operands
#pragma unroll
      for (int cc = 0; cc < 2; ++cc) {
        const int ko = ((cc * 4 + quad) ^ (l16 & 7)) * 8;
        kf[0][cc][0] = *(const bf16x8*)(lKb + (l16) * 64 + ko);
        kf[0][cc][1] = *(const bf16x8*)(lKb + (16 + l16) * 64 + ko);
      }
#pragma unroll
      for (int nb = 0; nb < 4; ++nb)
        av[0][nb] = *(const bf16x8*)(lVb + (nb * 16 + l16) * 128
                                     + ((quad ^ (l16 & 7)) * 8));
#pragma unroll
      for (int c = 0; c < 4; ++c) {
        const int buf = c & 1, nbuf = buf ^ 1;
        floatx4 sa[2], sb[2];
        sa[0] = vzero; sa[1] = vzero; sb[0] = vzero; sb[1] = vzero;
        __builtin_amdgcn_s_setprio(1);
#pragma unroll
        for (int cc = 0; cc < 2; ++cc)
#pragma unroll
          for (int mb = 0; mb < 2; ++mb) {
            sa[mb] = __builtin_amdgcn_mfma_f32_16x16x32_bf16(kf[buf][cc][0], qa[mb][cc], sa[mb], 0, 0, 0);
            sb[mb] = __builtin_amdgcn_mfma_f32_16x16x32_bf16(kf[buf][cc][1], qa[mb][cc], sb[mb], 0, 0, 0);
          }
        __builtin_amdgcn_s_setprio(0);
        if (c < 3) {  // prefetch chunk c+1 operands; latency hides under exp2
#pragma unroll
          for (int cc = 0; cc < 2; ++cc) {
            const int ko = (((cc * 4 + quad)) ^ (l16 & 7)) * 8;
            kf[nbuf][cc][0] = *(const bf16x8*)(lKb + ((c + 1) * 32 + l16) * 64 + ko);
            kf[nbuf][cc][1] = *(const bf16x8*)(lKb + ((c + 1) * 32 + 16 + l16) * 64 + ko);
          }
          const int chn = ((c + 1) * 4 + quad) ^ (l16 & 7);
#pragma unroll
          for (int nb = 0; nb < 4; ++nb)
            av[nbuf][nb] = *(const bf16x8*)(lVb + (nb * 16 + l16) * 128 + chn * 8);
        }
        exp_pv(sa, sb, av[buf]);
      }
    };

    stage(0, 0);
#pragma unroll 1
    for (int s0 = 0; s0 < SS; s0 += 256) {
      __syncthreads();                  // drains stage->buf0; buf1 readers done
      stage(1, s0 + 128);
      compute_clean(lK[0], lV[0]);
      __syncthreads();                  // drains stage->buf1; buf0 readers done
      if (s0 + 256 < SS) stage(0, s0 + 256);
      compute_clean(lK[1], lV[1]);
    }
  } else {
    // ---- masked fallback: exact R1 loop ----
    auto compute_masked = [&](const bf16_t* __restrict__ lKb,
                              const bf16_t* __restrict__ lVb, int s0) {
#pragma unroll
      for (int c = 0; c < 4; ++c) {
        floatx4 sa[2], sb[2];
        sa[0] = vzero; sa[1] = vzero; sb[0] = vzero; sb[1] = vzero;
#pragma unroll
        for (int cc = 0; cc < 2; ++cc) {
          const int ko = ((cc * 4 + quad) ^ (l16 & 7)) * 8;
          bf16x8 kf0 = *(const bf16x8*)(lKb + (c * 32 + l16) * 64 + ko);
          bf16x8 kf1 = *(const bf16x8*)(lKb + (c * 32 + 16 + l16) * 64 + ko);
          __builtin_amdgcn_s_setprio(1);
#pragma unroll
          for (int mb = 0; mb < 2; ++mb) {
            sa[mb] = __builtin_amdgcn_mfma_f32_16x16x32_bf16(kf0, qa[mb][cc], sa[mb], 0, 0, 0);
            sb[mb] = __builtin_amdgcn_mfma_f32_16x16x32_bf16(kf1, qa[mb][cc], sb[mb], 0, 0, 0);
          }
          __builtin_amdgcn_s_setprio(0);
        }
        const int4 m0 = *(const int4*)(maskb + s0 + c * 32 + quad * 4);
        const int4 m1 = *(const int4*)(maskb + s0 + c * 32 + 16 + quad * 4);
#pragma unroll
        for (int mb = 0; mb < 2; ++mb) {
          if (m0.x == 0) sa[mb][0] = -1e30f;
          if (m0.y == 0) sa[mb][1] = -1e30f;
          if (m0.z == 0) sa[mb][2] = -1e30f;
          if (m0.w == 0) sa[mb][3] = -1e30f;
          if (m1.x == 0) sb[mb][0] = -1e30f;
          if (m1.y == 0) sb[mb][1] = -1e30f;
          if (m1.z == 0) sb[mb][2] = -1e30f;
          if (m1.w == 0) sb[mb][3] = -1e30f;
        }
        const int ch = (c * 4 + quad) ^ (l16 & 7);
        bf16x8 av[4];
#pragma unroll
        for (int nb = 0; nb < 4; ++nb)
          av[nb] = *(const bf16x8*)(lVb + (nb * 16 + l16) * 128 + ch * 8);
        exp_pv(sa, sb, av);
      }
    };

    stage(0, 0);
#pragma unroll 1
    for (int s0 = 0; s0 < SS; s0 += 256) {
      __syncthreads();
      stage(1, s0 + 128);
      compute_masked(lK[0], lV[0], s0);
      __syncthreads();
      if (s0 + 256 < SS) stage(0, s0 + 256);
      compute_masked(lK[1], lV[1], s0 + 128);
    }
  }

  // ---- epilogue: O^T cols=qrow=l16, rows=dh=nb*16+quad*4+r -> 8B stores ----
#pragma unroll
  for (int mb = 0; mb < 2; ++mb) {
    float tot = lsum[mb];
    tot += __shfl_xor(tot, 16);
    tot += __shfl_xor(tot, 32);       // sum across the 4 quad-lanes of this qrow
    const float inv = 1.0f / tot;
    const size_t qrow = qrow0 + wave * 32 + mb * 16 + l16;
#pragma unroll
    for (int nb = 0; nb < 4; ++nb) {
      bf16x4 o = {(bf16_t)(cacc[mb][nb][0] * inv), (bf16_t)(cacc[mb][nb][1] * inv),
                  (bf16_t)(cacc[mb][nb][2] * inv), (bf16_t)(cacc[mb][nb][3] * inv)};
      *(bf16x4*)(ctx + qrow * DM + h * DHD + nb * 16 + quad * 4) = o;
    }
  }
}

// ---------------------------------------------------------------------------
extern "C" void kernel_launch(void* const* d_in, const int* in_sizes, int n_in,
                              void* d_out, int out_size, void* d_ws, size_t ws_size,
                              hipStream_t stream)
{
  (void)in_sizes; (void)n_in; (void)out_size; (void)ws_size;
  const float* reaction = (const float*)d_in[0];
  const int*   mask     = (const int*)d_in[1];
  const float* Wq = (const float*)d_in[2];
  const float* Wk = (const float*)d_in[3];
  const float* Wv = (const float*)d_in[4];
  const float* Wo = (const float*)d_in[5];
  const float* bo = (const float*)d_in[6];
  const float* W1 = (const float*)d_in[7];
  const float* b1 = (const float*)d_in[8];
  const float* W2 = (const float*)d_in[9];
  const float* b2 = (const float*)d_in[10];
  const float* g_sa = (const float*)d_in[11];
  const float* b_sa = (const float*)d_in[12];
  const float* g_ff = (const float*)d_in[13];
  const float* b_ff = (const float*)d_in[14];
  float* out = (float*)d_out;

  char* ws = (char*)d_ws;
  size_t off = 0;
  auto take = [&](size_t bytes) -> char* {
    char* p = ws + off;
    off += (bytes + 255) & ~(size_t)255;
    return p;
  };

  bf16_t* xln   = (bf16_t*)take((size_t)MT * DM * 2);       // LN1 out; reused as LN2 out
  bf16_t* WqkvT = (bf16_t*)take((size_t)3 * DM * DM * 2);   // [1536][512]
  bf16_t* WoT   = (bf16_t*)take((size_t)DM * DM * 2);
  bf16_t* W1T   = (bf16_t*)take((size_t)FFD * DM * 2);
  bf16_t* W2T   = (bf16_t*)take((size_t)DM * FFD * 2);
  bf16_t* qb    = (bf16_t*)take((size_t)MT * DM * 2);       // qb..ctx contiguous 32MB,
  bf16_t* kb    = (bf16_t*)take((size_t)MT * DM * 2);       // reused as FFN hidden h
  bf16_t* vtb   = (bf16_t*)take((size_t)DM * MT * 2);       // V transposed [D, M], sigma-permuted
  bf16_t* ctx   = (bf16_t*)take((size_t)MT * DM * 2);
  float*  x2    = (float*)take((size_t)MT * DM * 4);
  bf16_t* yb    = xln;
  bf16_t* hb    = qb;   // 8192*2048 bf16 = 32MB over qb/kb/vtb/ctx (all dead by then)

  // LN1 + all weight transposes in one dispatch (independent work)
  prep_ln<<<5120, 256, 0, stream>>>(reaction, g_sa, b_sa, xln,
                                    Wq, Wk, Wv, Wo, W1, W2, WqkvT, WoT, W1T, W2T);

  // Fused QKV projection (Q pre-scaled, V stored transposed + sigma-permuted)
  gemm_bt<4, 4, 5><<<dim3(64, 12), 256, 0, stream>>>(xln, WqkvT, MT, 3 * DM, DM,
                                                     nullptr, nullptr, qb, nullptr, kb, vtb, MT);

  attn_kernel<<<dim3(SS / 128, HN, BB), 256, 0, stream>>>(qb, kb, vtb, mask, ctx);

  // Output projection + GELU + residual -> x2 (fp32); K=512, grid-limited
  // 2 blocks/CU -> BK=128 halves barrier drains (48KB LDS, fits 2/CU)
  gemm_bt<4, 2, 2, 128><<<dim3(64, 8), 256, 0, stream>>>(ctx, WoT, MT, DM, DM,
                                                         bo, reaction, nullptr, x2, nullptr, nullptr, 0);

  ln_kernel<<<MT / 4, 256, 0, stream>>>(x2, g_ff, b_ff, yb);
  // FFN1: 8-wave 128x256 tile -> grid (64,8)=2 blocks/CU x 8 waves (same
  // 16 waves/CU as 4-wave at 4/CU), staging/output -25%, barrier events halved
  gemm_bt<4, 4, 3, 64, 8><<<dim3(64, 8), 512, 0, stream>>>(yb, W1T, MT, FFD, DM,
                                                           b1, nullptr, hb, nullptr, nullptr, nullptr, 0);
  // FFN2: K=2048, grid-limited 2 blocks/CU -> BK=128 halves barrier drains
  gemm_bt<4, 2, 4, 128><<<dim3(64, 8), 256, 0, stream>>>(hb, W2T, MT, DM, FFD,
                                                         b2, x2, nullptr, out, nullptr, nullptr, 0);
}